// Round 8
// baseline (142.041 us; speedup 1.0000x reference)
//
#include <hip/hip_runtime.h>
#include <hip/hip_bf16.h>
#include <stdint.h>

#define NROWS 8192
#define DDIM  1024
#define NQ    30
#define MARGINF 2.0f
#define NPROJ 64

typedef __attribute__((ext_vector_type(8))) short bf16x8;   // 8 bf16 (4 VGPRs)
typedef __attribute__((ext_vector_type(4))) float f32x4;    // MFMA accum

static __device__ __forceinline__ unsigned short f2bf(float f) {
  union { float f; unsigned u; } c; c.f = f;
  return (unsigned short)((c.u + 0x7fffu + ((c.u >> 16) & 1u)) >> 16);  // RNE
}

static __device__ __forceinline__ void gload_lds16(const void* g, void* l) {
  __builtin_amdgcn_global_load_lds(
      (const __attribute__((address_space(1))) void*)g,
      (__attribute__((address_space(3))) void*)l, 16, 0, 0);
}

// ---------------- prep: bf16 cast + row norms + pos term + rowMin init ------
__global__ __launch_bounds__(256) void prep_kernel(
    const float* __restrict__ o1, const float* __restrict__ o2,
    unsigned short* __restrict__ o1b, unsigned short* __restrict__ o2b,
    float* __restrict__ a2, float* __restrict__ b2, float* __restrict__ posr,
    unsigned int* __restrict__ rowMin, int* __restrict__ flag)
{
  const int row = blockIdx.x;
  const int t = threadIdx.x;
  const float4* p1 = (const float4*)(o1 + (size_t)row * DDIM);
  const float4* p2 = (const float4*)(o2 + (size_t)row * DDIM);
  float4 x1 = p1[t];
  float4 x2 = p2[t];
  float s1, s2, sp;
  {
    float a0 = x1.x, a1 = x1.y, aa2 = x1.z, a3 = x1.w;
    float b0 = x2.x, b1 = x2.y, bb2 = x2.z, b3 = x2.w;
    s1 = a0*a0 + a1*a1 + aa2*aa2 + a3*a3;
    s2 = b0*b0 + b1*b1 + bb2*bb2 + b3*b3;
    float d0 = b0-a0, d1 = b1-a1, d2 = bb2-aa2, d3 = b3-a3;
    sp = d0*d0 + d1*d1 + d2*d2 + d3*d3;
    *(ushort4*)(o1b + (size_t)row * DDIM + t * 4) =
        make_ushort4(f2bf(a0), f2bf(a1), f2bf(aa2), f2bf(a3));
    *(ushort4*)(o2b + (size_t)row * DDIM + t * 4) =
        make_ushort4(f2bf(b0), f2bf(b1), f2bf(bb2), f2bf(b3));
  }
  for (int s = 1; s < 64; s <<= 1) {
    s1 += __shfl_xor(s1, s);
    s2 += __shfl_xor(s2, s);
    sp += __shfl_xor(sp, s);
  }
  __shared__ float r1[4], r2[4], rp[4];
  const int wv = t >> 6;
  if ((t & 63) == 0) { r1[wv] = s1; r2[wv] = s2; rp[wv] = sp; }
  __syncthreads();
  if (t == 0) {
    a2[row]   = r1[0] + r1[1] + r1[2] + r1[3];
    b2[row]   = r2[0] + r2[1] + r2[2] + r2[3];
    posr[row] = rp[0] + rp[1] + rp[2] + rp[3];
    rowMin[row] = 0x7F800000u;           // +inf bits
    if (row == 0) *flag = 0;
  }
}

// ============================================================================
// Projection GEMM (LDS-free): proj[16384][64] = X @ H^T, H = 64 Hadamard
// columns ±1/32 (exactly orthonormal in bf16). A-fragment of 16x16x32 MFMA is
// a CONTIGUOUS 16B at X[row*1024 + kt*32 + c32*8] -> direct global load
// (wave reads 16 rows x 64B contiguous). Full k-unroll, no barriers; compiler
// pipelines the 32 independent loads under MFMA. 256 blocks x 4 waves x 16
// rows. Also emits pnorm[i] = |proj_i|^2.
// ============================================================================
__global__ __launch_bounds__(256) void proj_kernel(
    const unsigned short* __restrict__ X,   // o1b||o2b, 16384 x 1024 bf16
    unsigned short* __restrict__ proj,      // 16384 x 64 bf16
    float* __restrict__ pnorm)              // 16384
{
  const int tid  = threadIdx.x;
  const int lane = tid & 63;
  const int wave = tid >> 6;
  const int rlane = lane & 15;
  const int c32   = lane >> 4;
  const int rowA  = blockIdx.x * 64 + wave * 16 + rlane;   // this lane's A row

  // H fragments: col p = ni*16+rlane, k = (kt&1)*32 + c32*8 + j (mod-64 part)
  bf16x8 hf[2][4];
#pragma unroll
  for (int par = 0; par < 2; ++par)
#pragma unroll
    for (int ni = 0; ni < 4; ++ni) {
      const int p = ni * 16 + rlane;
      bf16x8 v;
#pragma unroll
      for (int j = 0; j < 8; ++j) {
        const int k = par * 32 + c32 * 8 + j;
        v[j] = (short)((__popc(p & k) & 1) ? 0xBD00 : 0x3D00);  // -+1/32
      }
      hf[par][ni] = v;
    }

  f32x4 acc[4];
#pragma unroll
  for (int ni = 0; ni < 4; ++ni) acc[ni] = (f32x4)0.0f;

  const unsigned short* Arow = X + (size_t)rowA * DDIM + c32 * 8;
#pragma unroll
  for (int kt = 0; kt < 32; ++kt) {
    const bf16x8 af = *(const bf16x8*)(Arow + kt * 32);
#pragma unroll
    for (int ni = 0; ni < 4; ++ni)
      acc[ni] = __builtin_amdgcn_mfma_f32_16x16x32_bf16(af, hf[kt & 1][ni], acc[ni], 0, 0, 0);
  }

  // epilogue: C/D row = c32*4 + j (within the wave's 16-row tile)
#pragma unroll
  for (int j = 0; j < 4; ++j) {
    const int row = blockIdx.x * 64 + wave * 16 + (c32 << 2) + j;
    float s = 0.0f;
#pragma unroll
    for (int ni = 0; ni < 4; ++ni) {
      const float v = acc[ni][j];
      s += v * v;
      proj[(size_t)row * NPROJ + ni * 16 + rlane] = f2bf(v);
    }
#pragma unroll
    for (int m = 1; m < 16; m <<= 1) s += __shfl_xor(s, m);
    if (rlane == 0) pnorm[row] = s;
  }
}

// ============================================================================
// K=64 gram of projections -> rowMin of the CERTIFIED LOWER BOUND.
// Register-direct, no LDS/barriers. v2: wave tile 64x32 (acc 32 VGPR),
// __launch_bounds__(256,3) -> 12 waves/CU (was VGPR=256 -> 9% occupancy).
// Grid 64x16 = 1024 blocks; block = 128 rows x 8 steps of 64 cols (512 cols).
// B-frags double-buffered with static names (rule #20).
// ============================================================================
__global__ __launch_bounds__(256, 3) void gram64_kernel(
    const unsigned short* __restrict__ P,   // proj: 16384 x 64 bf16
    const float* __restrict__ pn,           // 16384
    unsigned int* __restrict__ rowMin)
{
  const int tid  = threadIdx.x;
  const int lane = tid & 63;
  const int wave = tid >> 6;
  const int wr = wave >> 1;               // 0..1 -> +0/+64 rows
  const int wc = wave & 1;                // 0..1 -> +0/+32 cols
  const int bm = blockIdx.x * 128;
  const int bg = blockIdx.y * 512;
  const int rlane = lane & 15;
  const int c32   = lane >> 4;

  // A fragments, loaded once (L2/L3-hit)
  bf16x8 af[4][2];
#pragma unroll
  for (int mi = 0; mi < 4; ++mi)
#pragma unroll
    for (int ks = 0; ks < 2; ++ks)
      af[mi][ks] = *(const bf16x8*)(
          P + (size_t)(bm + wr * 64 + mi * 16 + rlane) * NPROJ + ks * 32 + c32 * 8);

  float rmn[4][4];
#pragma unroll
  for (int mi = 0; mi < 4; ++mi)
#pragma unroll
    for (int j = 0; j < 4; ++j) rmn[mi][j] = __builtin_inff();

#define LOADB(buf, pnv, t) do { \
    const int bn_ = bg + (t) * 64 + wc * 32; \
    _Pragma("unroll") for (int ni = 0; ni < 2; ++ni) { \
      _Pragma("unroll") for (int ks = 0; ks < 2; ++ks) \
        buf[ni][ks] = *(const bf16x8*)( \
            P + (size_t)(NROWS + bn_ + ni * 16 + rlane) * NPROJ + ks * 32 + c32 * 8); \
      pnv[ni] = pn[NROWS + bn_ + ni * 16 + rlane]; \
    } \
  } while (0)

#define COMPUTE(buf, pnv) do { \
    f32x4 acc[4][2]; \
    _Pragma("unroll") for (int mi = 0; mi < 4; ++mi) \
    _Pragma("unroll") for (int ni = 0; ni < 2; ++ni) acc[mi][ni] = (f32x4)0.0f; \
    _Pragma("unroll") for (int mi = 0; mi < 4; ++mi) \
    _Pragma("unroll") for (int ni = 0; ni < 2; ++ni) \
    _Pragma("unroll") for (int ks = 0; ks < 2; ++ks) \
      acc[mi][ni] = __builtin_amdgcn_mfma_f32_16x16x32_bf16( \
          af[mi][ks], buf[ni][ks], acc[mi][ni], 0, 0, 0); \
    _Pragma("unroll") for (int mi = 0; mi < 4; ++mi) \
    _Pragma("unroll") for (int j = 0; j < 4; ++j) \
    _Pragma("unroll") for (int ni = 0; ni < 2; ++ni) \
      rmn[mi][j] = fminf(rmn[mi][j], pnv[ni] - 2.0f * acc[mi][ni][j]); \
  } while (0)

  bf16x8 bA[2][2], bB[2][2];
  float pA[2], pB[2];
  LOADB(bA, pA, 0);
#pragma unroll
  for (int t = 0; t < 8; t += 2) {
    LOADB(bB, pB, t + 1);                    // prefetch odd step
    COMPUTE(bA, pA);
    if (t + 2 < 8) LOADB(bA, pA, t + 2);     // prefetch next even step
    COMPUTE(bB, pB);
  }
#undef LOADB
#undef COMPUTE

  // epilogue: bound = pn[row] + min(pnB - 2*gram); C/D row=(lane>>4)*4+j
#pragma unroll
  for (int mi = 0; mi < 4; ++mi) {
#pragma unroll
    for (int j = 0; j < 4; ++j) {
      const int row = bm + wr * 64 + mi * 16 + (c32 << 2) + j;
      float mn = rmn[mi][j] + pn[row];
#pragma unroll
      for (int s = 1; s < 16; s <<= 1) mn = fminf(mn, __shfl_xor(mn, s));
      if (rlane == 0) atomicMin(&rowMin[row], __float_as_uint(fmaxf(mn, 0.0f)));
    }
  }
}

// ---------------- flag: any row with lower-bound min < 16 (dist < 4)? -------
// True dist<2 pair implies bound < ~7.1 incl. all rounding -> always caught.
// Benign data: bound ~ 2*chi2_64, P(<16) ~ 1e-21 -> never fires.
__global__ __launch_bounds__(256) void flag_kernel(const unsigned int* __restrict__ rowMin,
                                                   int* __restrict__ flag)
{
  const int i = blockIdx.x * 256 + threadIdx.x;
  if (i < NROWS && rowMin[i] < 0x41800000u /* bits(16.0f) */) atomicExch(flag, 1);
}

// ---------------- 128^2 bf16 GEMM (flag-gated exact-path sq store) ----------
template<int STORE_SQ>
__global__ __launch_bounds__(256) void gemm_kernel(
    const unsigned short* __restrict__ A, const unsigned short* __restrict__ B,
    const float* __restrict__ a2, const float* __restrict__ b2,
    unsigned int* __restrict__ rowMin, const int* __restrict__ flag,
    float* __restrict__ sqbuf, int jBase, int chunkCols)
{
  if (STORE_SQ) { if (*flag == 0) return; }   // never taken on benign data
  __shared__ __align__(16) unsigned short lA[128 * 32];
  __shared__ __align__(16) unsigned short lB[128 * 32];
  const int tid  = threadIdx.x;
  const int lane = tid & 63;
  const int wave = tid >> 6;
  const int bm = blockIdx.y * 128;
  const int bn = blockIdx.x * 128;
  const int wm = (wave >> 1) * 64;
  const int wn = (wave & 1) * 64;

  f32x4 acc[4][4];
#pragma unroll
  for (int mi = 0; mi < 4; ++mi)
#pragma unroll
    for (int ni = 0; ni < 4; ++ni)
      acc[mi][ni] = (f32x4)0.0f;

  const unsigned short* Ab = A + (size_t)bm * DDIM;
  const unsigned short* Bb = B + (size_t)(jBase + bn) * DDIM;
  const int stRow  = lane >> 2;
  const int stColH = (lane & 3) * 8;

  for (int kt = 0; kt < DDIM / 32; ++kt) {
#pragma unroll
    for (int p = 0; p < 2; ++p) {
      const int off = (p * 4 + wave) * 1024;
      const int r0  = off >> 6;
      gload_lds16(Ab + (size_t)(r0 + stRow) * DDIM + kt * 32 + stColH, (char*)lA + off);
      gload_lds16(Bb + (size_t)(r0 + stRow) * DDIM + kt * 32 + stColH, (char*)lB + off);
    }
    __syncthreads();

    bf16x8 af[4], bfr[4];
#pragma unroll
    for (int mi = 0; mi < 4; ++mi) {
      const int r = wm + mi * 16 + (lane & 15);
      af[mi] = *(const bf16x8*)((const char*)lA + r * 64 + (lane >> 4) * 16);
    }
#pragma unroll
    for (int ni = 0; ni < 4; ++ni) {
      const int r = wn + ni * 16 + (lane & 15);
      bfr[ni] = *(const bf16x8*)((const char*)lB + r * 64 + (lane >> 4) * 16);
    }
#pragma unroll
    for (int mi = 0; mi < 4; ++mi)
#pragma unroll
      for (int ni = 0; ni < 4; ++ni)
        acc[mi][ni] = __builtin_amdgcn_mfma_f32_16x16x32_bf16(af[mi], bfr[ni], acc[mi][ni], 0, 0, 0);
    __syncthreads();
  }

  if (STORE_SQ == 0) {
#pragma unroll
    for (int mi = 0; mi < 4; ++mi) {
#pragma unroll
      for (int j = 0; j < 4; ++j) {
        const int i = bm + wm + mi * 16 + ((lane >> 4) << 2) + j;
        const float av = a2[i];
        float mn = __builtin_inff();
#pragma unroll
        for (int ni = 0; ni < 4; ++ni) {
          const int jj = bn + wn + ni * 16 + (lane & 15);
          mn = fminf(mn, av + b2[jj] - 2.0f * acc[mi][ni][j]);
        }
#pragma unroll
        for (int s = 1; s < 16; s <<= 1) mn = fminf(mn, __shfl_xor(mn, s));
        if ((lane & 15) == 0) atomicMin(&rowMin[i], __float_as_uint(fmaxf(mn, 0.0f)));
      }
    }
  } else {
#pragma unroll
    for (int mi = 0; mi < 4; ++mi) {
#pragma unroll
      for (int j = 0; j < 4; ++j) {
        const int i = bm + wm + mi * 16 + ((lane >> 4) << 2) + j;
        const float av = a2[i];
#pragma unroll
        for (int ni = 0; ni < 4; ++ni) {
          const int jj = bn + wn + ni * 16 + (lane & 15);
          sqbuf[(size_t)i * chunkCols + jj] = av + b2[jBase + jj] - 2.0f * acc[mi][ni][j];
        }
      }
    }
  }
}

// ---------------- exact top-30 per row (fallback; flag-gated) ---------------
template<int VPL>
__global__ __launch_bounds__(64) void select_kernel(
    const float* __restrict__ sqbuf, const int* __restrict__ flag,
    float* __restrict__ tv, int* __restrict__ ti, int jBase, int isFirst)
{
  if (*flag == 0) return;
  const int row = blockIdx.x, lane = threadIdx.x;
  const int CH = VPL * 64;
  float v[VPL];
#pragma unroll
  for (int q = 0; q < VPL; ++q)
    v[q] = sqbuf[(size_t)row * CH + q * 64 + lane];
  float cv; int ci;
  if (isFirst) { cv = __builtin_inff(); ci = 0x7fffffff; }
  else {
    cv = (lane < NQ) ? tv[row * 32 + lane] : __builtin_inff();
    ci = (lane < NQ) ? ti[row * 32 + lane] : 0x7fffffff;
  }
  for (int k = 0; k < NQ; ++k) {
    float mv = cv; int mi_ = ci;
#pragma unroll
    for (int q = 0; q < VPL; ++q) {
      const int col = jBase + q * 64 + lane;
      const bool b = (v[q] < mv) || (v[q] == mv && col < mi_);
      mv  = b ? v[q] : mv;
      mi_ = b ? col  : mi_;
    }
#pragma unroll
    for (int s = 1; s < 64; s <<= 1) {
      const float ov = __shfl_xor(mv, s);
      const int   oi = __shfl_xor(mi_, s);
      const bool b = (ov < mv) || (ov == mv && oi < mi_);
      mv  = b ? ov : mv;
      mi_ = b ? oi : mi_;
    }
    if (mi_ == ci) cv = __builtin_inff();
    else if (mi_ >= jBase) {
      const int rel = mi_ - jBase;
      if ((rel & 63) == lane) {
        const int lq = rel >> 6;
#pragma unroll
        for (int q = 0; q < VPL; ++q) if (q == lq) v[q] = __builtin_inff();
      }
    }
    if (lane == 0) { tv[row * 32 + k] = mv; ti[row * 32 + k] = mi_; }
  }
}

// ---------------- final reduction ------------------------------------------
__global__ __launch_bounds__(256) void final_kernel(
    const float* __restrict__ posr, const float* __restrict__ tv,
    const int* __restrict__ ti, const int* __restrict__ rn,
    const int* __restrict__ flag, float* __restrict__ out)
{
  const int t = threadIdx.x;
  const int useNeg = (*flag != 0);
  double ps = 0.0, ns = 0.0;
  for (int r = t; r < NROWS; r += 256) {
    ps += (double)posr[r];
    if (useNeg) {
      int k = rn[r];
      const int sel = ti[r * 32 + k];
      if (sel == r) k = (k + 1) % NQ;
      const float d = sqrtf(fmaxf(tv[r * 32 + k], 0.0f));
      ns += (double)fmaxf(MARGINF - d, 0.0f);
    }
  }
  __shared__ double sp[256], sn[256];
  sp[t] = ps; sn[t] = ns;
  __syncthreads();
  for (int s = 128; s > 0; s >>= 1) {
    if (t < s) { sp[t] += sp[t + s]; sn[t] += sn[t + s]; }
    __syncthreads();
  }
  if (t == 0) out[0] = (float)(sp[0] / NROWS + sn[0] / NROWS);
}

extern "C" void kernel_launch(void* const* d_in, const int* in_sizes, int n_in,
                              void* d_out, int out_size, void* d_ws, size_t ws_size,
                              hipStream_t stream) {
  (void)in_sizes; (void)n_in; (void)out_size;
  const float* o1 = (const float*)d_in[0];
  const float* o2 = (const float*)d_in[1];
  const int*   rn = (const int*)d_in[2];
  float* out = (float*)d_out;

  char* ws = (char*)d_ws;
  size_t off = 0;
  auto alloc = [&](size_t b) { void* p = ws + off; off += (b + 255) & ~(size_t)255; return p; };
  unsigned short* o1b = (unsigned short*)alloc((size_t)NROWS * DDIM * 2);  // 16 MB
  unsigned short* o2b = (unsigned short*)alloc((size_t)NROWS * DDIM * 2);  // 16 MB (contiguous after o1b)
  float* a2   = (float*)alloc((size_t)NROWS * 4);
  float* b2   = (float*)alloc((size_t)NROWS * 4);
  float* posr = (float*)alloc((size_t)NROWS * 4);
  unsigned int* rowMin = (unsigned int*)alloc((size_t)NROWS * 4);
  int*   flag = (int*)alloc(256);
  float* tv   = (float*)alloc((size_t)NROWS * 32 * 4);
  int*   ti   = (int*)alloc((size_t)NROWS * 32 * 4);
  unsigned short* proj = (unsigned short*)alloc((size_t)2 * NROWS * NPROJ * 2);  // 2 MB
  float* pnorm = (float*)alloc((size_t)2 * NROWS * 4);                           // 128 KB
  const size_t remain = ws_size > off ? ws_size - off : 0;
  int chunk;
  if      (remain >= (size_t)NROWS * 8192 * 4) chunk = 8192;
  else if (remain >= (size_t)NROWS * 2048 * 4) chunk = 2048;
  else if (remain >= (size_t)NROWS * 512 * 4)  chunk = 512;
  else                                         chunk = 128;
  float* sqbuf = (float*)(ws + off);

  prep_kernel<<<NROWS, 256, 0, stream>>>(o1, o2, o1b, o2b, a2, b2, posr, rowMin, flag);
  proj_kernel<<<2 * NROWS / 64, 256, 0, stream>>>(o1b, proj, pnorm);
  gram64_kernel<<<dim3(64, 16), 256, 0, stream>>>(proj, pnorm, rowMin);
  flag_kernel<<<dim3(NROWS / 256), 256, 0, stream>>>(rowMin, flag);

  const int nch = NROWS / chunk;
  for (int c = 0; c < nch; ++c) {
    gemm_kernel<1><<<dim3(chunk / 128, 64), 256, 0, stream>>>(o1b, o2b, a2, b2, rowMin, flag,
                                                              sqbuf, c * chunk, chunk);
    const int first = (c == 0);
    if      (chunk == 8192) select_kernel<128><<<NROWS, 64, 0, stream>>>(sqbuf, flag, tv, ti, c * chunk, first);
    else if (chunk == 2048) select_kernel<32><<<NROWS, 64, 0, stream>>>(sqbuf, flag, tv, ti, c * chunk, first);
    else if (chunk == 512)  select_kernel<8><<<NROWS, 64, 0, stream>>>(sqbuf, flag, tv, ti, c * chunk, first);
    else                    select_kernel<2><<<NROWS, 64, 0, stream>>>(sqbuf, flag, tv, ti, c * chunk, first);
  }
  final_kernel<<<1, 256, 0, stream>>>(posr, tv, ti, rn, flag, out);
}

// Round 9
// 117.393 us; speedup vs baseline: 1.2100x; 1.2100x over previous
//
#include <hip/hip_runtime.h>
#include <hip/hip_bf16.h>
#include <stdint.h>

#define NROWS 8192
#define DDIM  1024
#define NQ    30
#define MARGINF 2.0f
#define NPROJ 64

typedef __attribute__((ext_vector_type(8))) short bf16x8;   // 8 bf16 (4 VGPRs)
typedef __attribute__((ext_vector_type(4))) float f32x4;    // MFMA accum

static __device__ __forceinline__ unsigned short f2bf(float f) {
  union { float f; unsigned u; } c; c.f = f;
  return (unsigned short)((c.u + 0x7fffu + ((c.u >> 16) & 1u)) >> 16);  // RNE
}

static __device__ __forceinline__ void gload_lds16(const void* g, void* l) {
  __builtin_amdgcn_global_load_lds(
      (const __attribute__((address_space(1))) void*)g,
      (__attribute__((address_space(3))) void*)l, 16, 0, 0);
}

// ---------------- prep: bf16 cast + row norms + pos term + rowMin init ------
__global__ __launch_bounds__(256) void prep_kernel(
    const float* __restrict__ o1, const float* __restrict__ o2,
    unsigned short* __restrict__ o1b, unsigned short* __restrict__ o2b,
    float* __restrict__ a2, float* __restrict__ b2, float* __restrict__ posr,
    unsigned int* __restrict__ rowMin, int* __restrict__ flag)
{
  const int row = blockIdx.x;
  const int t = threadIdx.x;
  const float4* p1 = (const float4*)(o1 + (size_t)row * DDIM);
  const float4* p2 = (const float4*)(o2 + (size_t)row * DDIM);
  float4 x1 = p1[t];
  float4 x2 = p2[t];
  float s1, s2, sp;
  {
    float a0 = x1.x, a1 = x1.y, aa2 = x1.z, a3 = x1.w;
    float b0 = x2.x, b1 = x2.y, bb2 = x2.z, b3 = x2.w;
    s1 = a0*a0 + a1*a1 + aa2*aa2 + a3*a3;
    s2 = b0*b0 + b1*b1 + bb2*bb2 + b3*b3;
    float d0 = b0-a0, d1 = b1-a1, d2 = bb2-aa2, d3 = b3-a3;
    sp = d0*d0 + d1*d1 + d2*d2 + d3*d3;
    *(ushort4*)(o1b + (size_t)row * DDIM + t * 4) =
        make_ushort4(f2bf(a0), f2bf(a1), f2bf(aa2), f2bf(a3));
    *(ushort4*)(o2b + (size_t)row * DDIM + t * 4) =
        make_ushort4(f2bf(b0), f2bf(b1), f2bf(bb2), f2bf(b3));
  }
  for (int s = 1; s < 64; s <<= 1) {
    s1 += __shfl_xor(s1, s);
    s2 += __shfl_xor(s2, s);
    sp += __shfl_xor(sp, s);
  }
  __shared__ float r1[4], r2[4], rp[4];
  const int wv = t >> 6;
  if ((t & 63) == 0) { r1[wv] = s1; r2[wv] = s2; rp[wv] = sp; }
  __syncthreads();
  if (t == 0) {
    a2[row]   = r1[0] + r1[1] + r1[2] + r1[3];
    b2[row]   = r2[0] + r2[1] + r2[2] + r2[3];
    posr[row] = rp[0] + rp[1] + rp[2] + rp[3];
    rowMin[row] = 0x7F800000u;           // +inf bits
    if (row == 0) *flag = 0;
  }
}

// ============================================================================
// Projection GEMM (LDS-free): proj[16384][64] = X @ H^T, H = 64 Hadamard
// columns ±1/32 (exactly orthonormal in bf16). A-fragment is a contiguous
// 16B at X[row*1024 + kt*32 + c32*8] -> direct global load. Full k-unroll,
// no barriers. Also emits pnorm[i] = |proj_i|^2.
// ============================================================================
__global__ __launch_bounds__(256) void proj_kernel(
    const unsigned short* __restrict__ X,   // o1b||o2b, 16384 x 1024 bf16
    unsigned short* __restrict__ proj,      // 16384 x 64 bf16
    float* __restrict__ pnorm)              // 16384
{
  const int tid  = threadIdx.x;
  const int lane = tid & 63;
  const int wave = tid >> 6;
  const int rlane = lane & 15;
  const int c32   = lane >> 4;
  const int rowA  = blockIdx.x * 64 + wave * 16 + rlane;   // this lane's A row

  bf16x8 hf[2][4];
#pragma unroll
  for (int par = 0; par < 2; ++par)
#pragma unroll
    for (int ni = 0; ni < 4; ++ni) {
      const int p = ni * 16 + rlane;
      bf16x8 v;
#pragma unroll
      for (int j = 0; j < 8; ++j) {
        const int k = par * 32 + c32 * 8 + j;
        v[j] = (short)((__popc(p & k) & 1) ? 0xBD00 : 0x3D00);  // -+1/32
      }
      hf[par][ni] = v;
    }

  f32x4 acc[4];
#pragma unroll
  for (int ni = 0; ni < 4; ++ni) acc[ni] = (f32x4)0.0f;

  const unsigned short* Arow = X + (size_t)rowA * DDIM + c32 * 8;
#pragma unroll
  for (int kt = 0; kt < 32; ++kt) {
    const bf16x8 af = *(const bf16x8*)(Arow + kt * 32);
#pragma unroll
    for (int ni = 0; ni < 4; ++ni)
      acc[ni] = __builtin_amdgcn_mfma_f32_16x16x32_bf16(af, hf[kt & 1][ni], acc[ni], 0, 0, 0);
  }

#pragma unroll
  for (int j = 0; j < 4; ++j) {
    const int row = blockIdx.x * 64 + wave * 16 + (c32 << 2) + j;
    float s = 0.0f;
#pragma unroll
    for (int ni = 0; ni < 4; ++ni) {
      const float v = acc[ni][j];
      s += v * v;
      proj[(size_t)row * NPROJ + ni * 16 + rlane] = f2bf(v);
    }
#pragma unroll
    for (int m = 1; m < 16; m <<= 1) s += __shfl_xor(s, m);
    if (rlane == 0) pnorm[row] = s;
  }
}

// ============================================================================
// K=64 gram of projections -> GLOBAL min of the certified lower bound.
// v3: grid 64x8 = 512 blocks (R7's L2-friendly sweep; R8's 1024-block grid
// thrashed L2: FETCH 33->82 MB), but 512 threads (8 waves 2x4), wave tile
// 64x32 -> VGPR ~130 with launch_bounds(512,3) = 12 waves/CU (4x R7).
// Only the flag needs the min -> single block-min atomicMin on rowMin[0].
// ============================================================================
__global__ __launch_bounds__(512, 3) void gram64_kernel(
    const unsigned short* __restrict__ P,   // proj: 16384 x 64 bf16
    const float* __restrict__ pn,           // 16384
    unsigned int* __restrict__ rowMin)
{
  const int tid  = threadIdx.x;
  const int lane = tid & 63;
  const int wave = tid >> 6;
  const int wr = wave >> 2;               // 0..1 -> +0/+64 rows
  const int wc = wave & 3;                // 0..3 -> +0/32/64/96 cols
  const int bm = blockIdx.x * 128;
  const int bg = blockIdx.y * 1024;
  const int rlane = lane & 15;
  const int c32   = lane >> 4;

  // A fragments, loaded once (L2-hit)
  bf16x8 af[4][2];
#pragma unroll
  for (int mi = 0; mi < 4; ++mi)
#pragma unroll
    for (int ks = 0; ks < 2; ++ks)
      af[mi][ks] = *(const bf16x8*)(
          P + (size_t)(bm + wr * 64 + mi * 16 + rlane) * NPROJ + ks * 32 + c32 * 8);

  float rmn[4][4];
#pragma unroll
  for (int mi = 0; mi < 4; ++mi)
#pragma unroll
    for (int j = 0; j < 4; ++j) rmn[mi][j] = __builtin_inff();

#define LOADB(buf, pnv, t) do { \
    const int bn_ = bg + (t) * 128 + wc * 32; \
    _Pragma("unroll") for (int ni = 0; ni < 2; ++ni) { \
      _Pragma("unroll") for (int ks = 0; ks < 2; ++ks) \
        buf[ni][ks] = *(const bf16x8*)( \
            P + (size_t)(NROWS + bn_ + ni * 16 + rlane) * NPROJ + ks * 32 + c32 * 8); \
      pnv[ni] = pn[NROWS + bn_ + ni * 16 + rlane]; \
    } \
  } while (0)

#define COMPUTE(buf, pnv) do { \
    f32x4 acc[4][2]; \
    _Pragma("unroll") for (int mi = 0; mi < 4; ++mi) \
    _Pragma("unroll") for (int ni = 0; ni < 2; ++ni) acc[mi][ni] = (f32x4)0.0f; \
    _Pragma("unroll") for (int mi = 0; mi < 4; ++mi) \
    _Pragma("unroll") for (int ni = 0; ni < 2; ++ni) \
    _Pragma("unroll") for (int ks = 0; ks < 2; ++ks) \
      acc[mi][ni] = __builtin_amdgcn_mfma_f32_16x16x32_bf16( \
          af[mi][ks], buf[ni][ks], acc[mi][ni], 0, 0, 0); \
    _Pragma("unroll") for (int mi = 0; mi < 4; ++mi) \
    _Pragma("unroll") for (int j = 0; j < 4; ++j) \
    _Pragma("unroll") for (int ni = 0; ni < 2; ++ni) \
      rmn[mi][j] = fminf(rmn[mi][j], pnv[ni] - 2.0f * acc[mi][ni][j]); \
  } while (0)

  bf16x8 bA[2][2], bB[2][2];
  float pA[2], pB[2];
  LOADB(bA, pA, 0);
#pragma unroll
  for (int t = 0; t < 8; t += 2) {
    LOADB(bB, pB, t + 1);                    // prefetch odd step
    COMPUTE(bA, pA);
    if (t + 2 < 8) LOADB(bA, pA, t + 2);     // prefetch next even step
    COMPUTE(bB, pB);
  }
#undef LOADB
#undef COMPUTE

  // epilogue: fold pn[row] in, min over all regs, 64-lane reduce, one atomic.
  float tot = __builtin_inff();
#pragma unroll
  for (int mi = 0; mi < 4; ++mi) {
#pragma unroll
    for (int j = 0; j < 4; ++j) {
      const int row = bm + wr * 64 + mi * 16 + (c32 << 2) + j;
      tot = fminf(tot, rmn[mi][j] + pn[row]);
    }
  }
#pragma unroll
  for (int s = 1; s < 64; s <<= 1) tot = fminf(tot, __shfl_xor(tot, s));
  if (lane == 0) atomicMin(&rowMin[0], __float_as_uint(fmaxf(tot, 0.0f)));
}

// ---------------- flag: any row with lower-bound min < 16 (dist < 4)? -------
// True dist<2 pair implies bound < ~7.1 incl. all rounding -> always caught.
// Benign data: bound ~ 2*chi2_64, P(<16) ~ 1e-21 -> never fires.
__global__ __launch_bounds__(256) void flag_kernel(const unsigned int* __restrict__ rowMin,
                                                   int* __restrict__ flag)
{
  const int i = blockIdx.x * 256 + threadIdx.x;
  if (i < NROWS && rowMin[i] < 0x41800000u /* bits(16.0f) */) atomicExch(flag, 1);
}

// ---------------- 128^2 bf16 GEMM (flag-gated exact-path sq store) ----------
template<int STORE_SQ>
__global__ __launch_bounds__(256) void gemm_kernel(
    const unsigned short* __restrict__ A, const unsigned short* __restrict__ B,
    const float* __restrict__ a2, const float* __restrict__ b2,
    unsigned int* __restrict__ rowMin, const int* __restrict__ flag,
    float* __restrict__ sqbuf, int jBase, int chunkCols)
{
  if (STORE_SQ) { if (*flag == 0) return; }   // never taken on benign data
  __shared__ __align__(16) unsigned short lA[128 * 32];
  __shared__ __align__(16) unsigned short lB[128 * 32];
  const int tid  = threadIdx.x;
  const int lane = tid & 63;
  const int wave = tid >> 6;
  const int bm = blockIdx.y * 128;
  const int bn = blockIdx.x * 128;
  const int wm = (wave >> 1) * 64;
  const int wn = (wave & 1) * 64;

  f32x4 acc[4][4];
#pragma unroll
  for (int mi = 0; mi < 4; ++mi)
#pragma unroll
    for (int ni = 0; ni < 4; ++ni)
      acc[mi][ni] = (f32x4)0.0f;

  const unsigned short* Ab = A + (size_t)bm * DDIM;
  const unsigned short* Bb = B + (size_t)(jBase + bn) * DDIM;
  const int stRow  = lane >> 2;
  const int stColH = (lane & 3) * 8;

  for (int kt = 0; kt < DDIM / 32; ++kt) {
#pragma unroll
    for (int p = 0; p < 2; ++p) {
      const int off = (p * 4 + wave) * 1024;
      const int r0  = off >> 6;
      gload_lds16(Ab + (size_t)(r0 + stRow) * DDIM + kt * 32 + stColH, (char*)lA + off);
      gload_lds16(Bb + (size_t)(r0 + stRow) * DDIM + kt * 32 + stColH, (char*)lB + off);
    }
    __syncthreads();

    bf16x8 af[4], bfr[4];
#pragma unroll
    for (int mi = 0; mi < 4; ++mi) {
      const int r = wm + mi * 16 + (lane & 15);
      af[mi] = *(const bf16x8*)((const char*)lA + r * 64 + (lane >> 4) * 16);
    }
#pragma unroll
    for (int ni = 0; ni < 4; ++ni) {
      const int r = wn + ni * 16 + (lane & 15);
      bfr[ni] = *(const bf16x8*)((const char*)lB + r * 64 + (lane >> 4) * 16);
    }
#pragma unroll
    for (int mi = 0; mi < 4; ++mi)
#pragma unroll
      for (int ni = 0; ni < 4; ++ni)
        acc[mi][ni] = __builtin_amdgcn_mfma_f32_16x16x32_bf16(af[mi], bfr[ni], acc[mi][ni], 0, 0, 0);
    __syncthreads();
  }

  if (STORE_SQ == 0) {
#pragma unroll
    for (int mi = 0; mi < 4; ++mi) {
#pragma unroll
      for (int j = 0; j < 4; ++j) {
        const int i = bm + wm + mi * 16 + ((lane >> 4) << 2) + j;
        const float av = a2[i];
        float mn = __builtin_inff();
#pragma unroll
        for (int ni = 0; ni < 4; ++ni) {
          const int jj = bn + wn + ni * 16 + (lane & 15);
          mn = fminf(mn, av + b2[jj] - 2.0f * acc[mi][ni][j]);
        }
#pragma unroll
        for (int s = 1; s < 16; s <<= 1) mn = fminf(mn, __shfl_xor(mn, s));
        if ((lane & 15) == 0) atomicMin(&rowMin[i], __float_as_uint(fmaxf(mn, 0.0f)));
      }
    }
  } else {
#pragma unroll
    for (int mi = 0; mi < 4; ++mi) {
#pragma unroll
      for (int j = 0; j < 4; ++j) {
        const int i = bm + wm + mi * 16 + ((lane >> 4) << 2) + j;
        const float av = a2[i];
#pragma unroll
        for (int ni = 0; ni < 4; ++ni) {
          const int jj = bn + wn + ni * 16 + (lane & 15);
          sqbuf[(size_t)i * chunkCols + jj] = av + b2[jBase + jj] - 2.0f * acc[mi][ni][j];
        }
      }
    }
  }
}

// ---------------- exact top-30 per row (fallback; flag-gated) ---------------
template<int VPL>
__global__ __launch_bounds__(64) void select_kernel(
    const float* __restrict__ sqbuf, const int* __restrict__ flag,
    float* __restrict__ tv, int* __restrict__ ti, int jBase, int isFirst)
{
  if (*flag == 0) return;
  const int row = blockIdx.x, lane = threadIdx.x;
  const int CH = VPL * 64;
  float v[VPL];
#pragma unroll
  for (int q = 0; q < VPL; ++q)
    v[q] = sqbuf[(size_t)row * CH + q * 64 + lane];
  float cv; int ci;
  if (isFirst) { cv = __builtin_inff(); ci = 0x7fffffff; }
  else {
    cv = (lane < NQ) ? tv[row * 32 + lane] : __builtin_inff();
    ci = (lane < NQ) ? ti[row * 32 + lane] : 0x7fffffff;
  }
  for (int k = 0; k < NQ; ++k) {
    float mv = cv; int mi_ = ci;
#pragma unroll
    for (int q = 0; q < VPL; ++q) {
      const int col = jBase + q * 64 + lane;
      const bool b = (v[q] < mv) || (v[q] == mv && col < mi_);
      mv  = b ? v[q] : mv;
      mi_ = b ? col  : mi_;
    }
#pragma unroll
    for (int s = 1; s < 64; s <<= 1) {
      const float ov = __shfl_xor(mv, s);
      const int   oi = __shfl_xor(mi_, s);
      const bool b = (ov < mv) || (ov == mv && oi < mi_);
      mv  = b ? ov : mv;
      mi_ = b ? oi : mi_;
    }
    if (mi_ == ci) cv = __builtin_inff();
    else if (mi_ >= jBase) {
      const int rel = mi_ - jBase;
      if ((rel & 63) == lane) {
        const int lq = rel >> 6;
#pragma unroll
        for (int q = 0; q < VPL; ++q) if (q == lq) v[q] = __builtin_inff();
      }
    }
    if (lane == 0) { tv[row * 32 + k] = mv; ti[row * 32 + k] = mi_; }
  }
}

// ---------------- final reduction ------------------------------------------
__global__ __launch_bounds__(256) void final_kernel(
    const float* __restrict__ posr, const float* __restrict__ tv,
    const int* __restrict__ ti, const int* __restrict__ rn,
    const int* __restrict__ flag, float* __restrict__ out)
{
  const int t = threadIdx.x;
  const int useNeg = (*flag != 0);
  double ps = 0.0, ns = 0.0;
  for (int r = t; r < NROWS; r += 256) {
    ps += (double)posr[r];
    if (useNeg) {
      int k = rn[r];
      const int sel = ti[r * 32 + k];
      if (sel == r) k = (k + 1) % NQ;
      const float d = sqrtf(fmaxf(tv[r * 32 + k], 0.0f));
      ns += (double)fmaxf(MARGINF - d, 0.0f);
    }
  }
  __shared__ double sp[256], sn[256];
  sp[t] = ps; sn[t] = ns;
  __syncthreads();
  for (int s = 128; s > 0; s >>= 1) {
    if (t < s) { sp[t] += sp[t + s]; sn[t] += sn[t + s]; }
    __syncthreads();
  }
  if (t == 0) out[0] = (float)(sp[0] / NROWS + sn[0] / NROWS);
}

extern "C" void kernel_launch(void* const* d_in, const int* in_sizes, int n_in,
                              void* d_out, int out_size, void* d_ws, size_t ws_size,
                              hipStream_t stream) {
  (void)in_sizes; (void)n_in; (void)out_size;
  const float* o1 = (const float*)d_in[0];
  const float* o2 = (const float*)d_in[1];
  const int*   rn = (const int*)d_in[2];
  float* out = (float*)d_out;

  char* ws = (char*)d_ws;
  size_t off = 0;
  auto alloc = [&](size_t b) { void* p = ws + off; off += (b + 255) & ~(size_t)255; return p; };
  unsigned short* o1b = (unsigned short*)alloc((size_t)NROWS * DDIM * 2);  // 16 MB
  unsigned short* o2b = (unsigned short*)alloc((size_t)NROWS * DDIM * 2);  // 16 MB (contiguous after o1b)
  float* a2   = (float*)alloc((size_t)NROWS * 4);
  float* b2   = (float*)alloc((size_t)NROWS * 4);
  float* posr = (float*)alloc((size_t)NROWS * 4);
  unsigned int* rowMin = (unsigned int*)alloc((size_t)NROWS * 4);
  int*   flag = (int*)alloc(256);
  float* tv   = (float*)alloc((size_t)NROWS * 32 * 4);
  int*   ti   = (int*)alloc((size_t)NROWS * 32 * 4);
  unsigned short* proj = (unsigned short*)alloc((size_t)2 * NROWS * NPROJ * 2);  // 2 MB
  float* pnorm = (float*)alloc((size_t)2 * NROWS * 4);                           // 128 KB
  const size_t remain = ws_size > off ? ws_size - off : 0;
  int chunk;
  if      (remain >= (size_t)NROWS * 8192 * 4) chunk = 8192;
  else if (remain >= (size_t)NROWS * 2048 * 4) chunk = 2048;
  else if (remain >= (size_t)NROWS * 512 * 4)  chunk = 512;
  else                                         chunk = 128;
  float* sqbuf = (float*)(ws + off);

  prep_kernel<<<NROWS, 256, 0, stream>>>(o1, o2, o1b, o2b, a2, b2, posr, rowMin, flag);
  proj_kernel<<<2 * NROWS / 64, 256, 0, stream>>>(o1b, proj, pnorm);
  gram64_kernel<<<dim3(64, 8), 512, 0, stream>>>(proj, pnorm, rowMin);
  flag_kernel<<<dim3(NROWS / 256), 256, 0, stream>>>(rowMin, flag);

  const int nch = NROWS / chunk;
  for (int c = 0; c < nch; ++c) {
    gemm_kernel<1><<<dim3(chunk / 128, 64), 256, 0, stream>>>(o1b, o2b, a2, b2, rowMin, flag,
                                                              sqbuf, c * chunk, chunk);
    const int first = (c == 0);
    if      (chunk == 8192) select_kernel<128><<<NROWS, 64, 0, stream>>>(sqbuf, flag, tv, ti, c * chunk, first);
    else if (chunk == 2048) select_kernel<32><<<NROWS, 64, 0, stream>>>(sqbuf, flag, tv, ti, c * chunk, first);
    else if (chunk == 512)  select_kernel<8><<<NROWS, 64, 0, stream>>>(sqbuf, flag, tv, ti, c * chunk, first);
    else                    select_kernel<2><<<NROWS, 64, 0, stream>>>(sqbuf, flag, tv, ti, c * chunk, first);
  }
  final_kernel<<<1, 256, 0, stream>>>(posr, tv, ti, rn, flag, out);
}

// Round 10
// 84.349 us; speedup vs baseline: 1.6840x; 1.3918x over previous
//
#include <hip/hip_runtime.h>
#include <hip/hip_bf16.h>
#include <stdint.h>

#define NROWS 8192
#define DDIM  1024
#define NQ    30
#define MARGINF 2.0f
#define NPROJ 64

typedef __attribute__((ext_vector_type(8))) short bf16x8;   // 8 bf16 (4 VGPRs)
typedef __attribute__((ext_vector_type(4))) float f32x4;    // MFMA accum

static __device__ __forceinline__ unsigned short f2bf(float f) {
  union { float f; unsigned u; } c; c.f = f;
  return (unsigned short)((c.u + 0x7fffu + ((c.u >> 16) & 1u)) >> 16);  // RNE
}

static __device__ __forceinline__ void gload_lds16(const void* g, void* l) {
  __builtin_amdgcn_global_load_lds(
      (const __attribute__((address_space(1))) void*)g,
      (__attribute__((address_space(3))) void*)l, 16, 0, 0);
}

// ---------------- prep: bf16 cast + row norms + pos term + rowMin init ------
__global__ __launch_bounds__(256) void prep_kernel(
    const float* __restrict__ o1, const float* __restrict__ o2,
    unsigned short* __restrict__ o1b, unsigned short* __restrict__ o2b,
    float* __restrict__ a2, float* __restrict__ b2, float* __restrict__ posr,
    unsigned int* __restrict__ rowMin, int* __restrict__ flag)
{
  const int row = blockIdx.x;
  const int t = threadIdx.x;
  const float4* p1 = (const float4*)(o1 + (size_t)row * DDIM);
  const float4* p2 = (const float4*)(o2 + (size_t)row * DDIM);
  float4 x1 = p1[t];
  float4 x2 = p2[t];
  float s1, s2, sp;
  {
    float a0 = x1.x, a1 = x1.y, aa2 = x1.z, a3 = x1.w;
    float b0 = x2.x, b1 = x2.y, bb2 = x2.z, b3 = x2.w;
    s1 = a0*a0 + a1*a1 + aa2*aa2 + a3*a3;
    s2 = b0*b0 + b1*b1 + bb2*bb2 + b3*b3;
    float d0 = b0-a0, d1 = b1-a1, d2 = bb2-aa2, d3 = b3-a3;
    sp = d0*d0 + d1*d1 + d2*d2 + d3*d3;
    *(ushort4*)(o1b + (size_t)row * DDIM + t * 4) =
        make_ushort4(f2bf(a0), f2bf(a1), f2bf(aa2), f2bf(a3));
    *(ushort4*)(o2b + (size_t)row * DDIM + t * 4) =
        make_ushort4(f2bf(b0), f2bf(b1), f2bf(bb2), f2bf(b3));
  }
  for (int s = 1; s < 64; s <<= 1) {
    s1 += __shfl_xor(s1, s);
    s2 += __shfl_xor(s2, s);
    sp += __shfl_xor(sp, s);
  }
  __shared__ float r1[4], r2[4], rp[4];
  const int wv = t >> 6;
  if ((t & 63) == 0) { r1[wv] = s1; r2[wv] = s2; rp[wv] = sp; }
  __syncthreads();
  if (t == 0) {
    a2[row]   = r1[0] + r1[1] + r1[2] + r1[3];
    b2[row]   = r2[0] + r2[1] + r2[2] + r2[3];
    posr[row] = rp[0] + rp[1] + rp[2] + rp[3];
    rowMin[row] = 0x7F800000u;           // +inf bits
    if (row == 0) *flag = 0;
  }
}

// ============================================================================
// Projection GEMM (LDS-free): proj[16384][64] = X @ H^T, H = 64 Hadamard
// columns ±1/32 (exactly orthonormal in bf16). A-fragment is a contiguous
// 16B at X[row*1024 + kt*32 + c32*8] -> direct global load. Full k-unroll,
// no barriers. Also emits pnorm[i] = |proj_i|^2.
// ============================================================================
__global__ __launch_bounds__(256) void proj_kernel(
    const unsigned short* __restrict__ X,   // o1b||o2b, 16384 x 1024 bf16
    unsigned short* __restrict__ proj,      // 16384 x 64 bf16
    float* __restrict__ pnorm)              // 16384
{
  const int tid  = threadIdx.x;
  const int lane = tid & 63;
  const int wave = tid >> 6;
  const int rlane = lane & 15;
  const int c32   = lane >> 4;
  const int rowA  = blockIdx.x * 64 + wave * 16 + rlane;   // this lane's A row

  bf16x8 hf[2][4];
#pragma unroll
  for (int par = 0; par < 2; ++par)
#pragma unroll
    for (int ni = 0; ni < 4; ++ni) {
      const int p = ni * 16 + rlane;
      bf16x8 v;
#pragma unroll
      for (int j = 0; j < 8; ++j) {
        const int k = par * 32 + c32 * 8 + j;
        v[j] = (short)((__popc(p & k) & 1) ? 0xBD00 : 0x3D00);  // -+1/32
      }
      hf[par][ni] = v;
    }

  f32x4 acc[4];
#pragma unroll
  for (int ni = 0; ni < 4; ++ni) acc[ni] = (f32x4)0.0f;

  const unsigned short* Arow = X + (size_t)rowA * DDIM + c32 * 8;
#pragma unroll
  for (int kt = 0; kt < 32; ++kt) {
    const bf16x8 af = *(const bf16x8*)(Arow + kt * 32);
#pragma unroll
    for (int ni = 0; ni < 4; ++ni)
      acc[ni] = __builtin_amdgcn_mfma_f32_16x16x32_bf16(af, hf[kt & 1][ni], acc[ni], 0, 0, 0);
  }

#pragma unroll
  for (int j = 0; j < 4; ++j) {
    const int row = blockIdx.x * 64 + wave * 16 + (c32 << 2) + j;
    float s = 0.0f;
#pragma unroll
    for (int ni = 0; ni < 4; ++ni) {
      const float v = acc[ni][j];
      s += v * v;
      proj[(size_t)row * NPROJ + ni * 16 + rlane] = f2bf(v);
    }
#pragma unroll
    for (int m = 1; m < 16; m <<= 1) s += __shfl_xor(s, m);
    if (rlane == 0) pnorm[row] = s;
  }
}

// ============================================================================
// K=64 gram of projections -> GLOBAL min of the certified lower bound.
// v4: same compute as v3 (512 blocks x 8 waves, wave tile 64x32, FETCH 5.8 MB
// = fully L2-absorbed), but the epilogue's 4096 same-address atomics (R9:
// ~35cyc x 4096 serialized = 59us, the whole kernel time!) are replaced by an
// LDS block reduction -> ONE atomicMin per block (512 total).
// ============================================================================
__global__ __launch_bounds__(512, 3) void gram64_kernel(
    const unsigned short* __restrict__ P,   // proj: 16384 x 64 bf16
    const float* __restrict__ pn,           // 16384
    unsigned int* __restrict__ rowMin)
{
  __shared__ float sred[8];
  const int tid  = threadIdx.x;
  const int lane = tid & 63;
  const int wave = tid >> 6;
  const int wr = wave >> 2;               // 0..1 -> +0/+64 rows
  const int wc = wave & 3;                // 0..3 -> +0/32/64/96 cols
  const int bm = blockIdx.x * 128;
  const int bg = blockIdx.y * 1024;
  const int rlane = lane & 15;
  const int c32   = lane >> 4;

  // A fragments, loaded once (L2-hit)
  bf16x8 af[4][2];
#pragma unroll
  for (int mi = 0; mi < 4; ++mi)
#pragma unroll
    for (int ks = 0; ks < 2; ++ks)
      af[mi][ks] = *(const bf16x8*)(
          P + (size_t)(bm + wr * 64 + mi * 16 + rlane) * NPROJ + ks * 32 + c32 * 8);

  float rmn[4][4];
#pragma unroll
  for (int mi = 0; mi < 4; ++mi)
#pragma unroll
    for (int j = 0; j < 4; ++j) rmn[mi][j] = __builtin_inff();

#define LOADB(buf, pnv, t) do { \
    const int bn_ = bg + (t) * 128 + wc * 32; \
    _Pragma("unroll") for (int ni = 0; ni < 2; ++ni) { \
      _Pragma("unroll") for (int ks = 0; ks < 2; ++ks) \
        buf[ni][ks] = *(const bf16x8*)( \
            P + (size_t)(NROWS + bn_ + ni * 16 + rlane) * NPROJ + ks * 32 + c32 * 8); \
      pnv[ni] = pn[NROWS + bn_ + ni * 16 + rlane]; \
    } \
  } while (0)

#define COMPUTE(buf, pnv) do { \
    f32x4 acc[4][2]; \
    _Pragma("unroll") for (int mi = 0; mi < 4; ++mi) \
    _Pragma("unroll") for (int ni = 0; ni < 2; ++ni) acc[mi][ni] = (f32x4)0.0f; \
    _Pragma("unroll") for (int mi = 0; mi < 4; ++mi) \
    _Pragma("unroll") for (int ni = 0; ni < 2; ++ni) \
    _Pragma("unroll") for (int ks = 0; ks < 2; ++ks) \
      acc[mi][ni] = __builtin_amdgcn_mfma_f32_16x16x32_bf16( \
          af[mi][ks], buf[ni][ks], acc[mi][ni], 0, 0, 0); \
    _Pragma("unroll") for (int mi = 0; mi < 4; ++mi) \
    _Pragma("unroll") for (int j = 0; j < 4; ++j) \
    _Pragma("unroll") for (int ni = 0; ni < 2; ++ni) \
      rmn[mi][j] = fminf(rmn[mi][j], pnv[ni] - 2.0f * acc[mi][ni][j]); \
  } while (0)

  bf16x8 bA[2][2], bB[2][2];
  float pA[2], pB[2];
  LOADB(bA, pA, 0);
#pragma unroll
  for (int t = 0; t < 8; t += 2) {
    LOADB(bB, pB, t + 1);                    // prefetch odd step
    COMPUTE(bA, pA);
    if (t + 2 < 8) LOADB(bA, pA, t + 2);     // prefetch next even step
    COMPUTE(bB, pB);
  }
#undef LOADB
#undef COMPUTE

  // epilogue: fold pn[row] in, min over regs, 64-lane reduce, LDS block
  // reduce, ONE atomic per block (512 total; R9's 4096 same-address atomics
  // serialized to 59us).
  float tot = __builtin_inff();
#pragma unroll
  for (int mi = 0; mi < 4; ++mi) {
#pragma unroll
    for (int j = 0; j < 4; ++j) {
      const int row = bm + wr * 64 + mi * 16 + (c32 << 2) + j;
      tot = fminf(tot, rmn[mi][j] + pn[row]);
    }
  }
#pragma unroll
  for (int s = 1; s < 64; s <<= 1) tot = fminf(tot, __shfl_xor(tot, s));
  if (lane == 0) sred[wave] = tot;
  __syncthreads();
  if (tid == 0) {
    float m = sred[0];
#pragma unroll
    for (int w = 1; w < 8; ++w) m = fminf(m, sred[w]);
    atomicMin(&rowMin[0], __float_as_uint(fmaxf(m, 0.0f)));
  }
}

// ---------------- flag: any row with lower-bound min < 16 (dist < 4)? -------
// True dist<2 pair implies bound < ~7.1 incl. all rounding -> always caught.
// Benign data: bound ~ 2*chi2_64, P(<16) ~ 1e-21 -> never fires.
__global__ __launch_bounds__(256) void flag_kernel(const unsigned int* __restrict__ rowMin,
                                                   int* __restrict__ flag)
{
  const int i = blockIdx.x * 256 + threadIdx.x;
  if (i < NROWS && rowMin[i] < 0x41800000u /* bits(16.0f) */) atomicExch(flag, 1);
}

// ---------------- 128^2 bf16 GEMM (flag-gated exact-path sq store) ----------
template<int STORE_SQ>
__global__ __launch_bounds__(256) void gemm_kernel(
    const unsigned short* __restrict__ A, const unsigned short* __restrict__ B,
    const float* __restrict__ a2, const float* __restrict__ b2,
    unsigned int* __restrict__ rowMin, const int* __restrict__ flag,
    float* __restrict__ sqbuf, int jBase, int chunkCols)
{
  if (STORE_SQ) { if (*flag == 0) return; }   // never taken on benign data
  __shared__ __align__(16) unsigned short lA[128 * 32];
  __shared__ __align__(16) unsigned short lB[128 * 32];
  const int tid  = threadIdx.x;
  const int lane = tid & 63;
  const int wave = tid >> 6;
  const int bm = blockIdx.y * 128;
  const int bn = blockIdx.x * 128;
  const int wm = (wave >> 1) * 64;
  const int wn = (wave & 1) * 64;

  f32x4 acc[4][4];
#pragma unroll
  for (int mi = 0; mi < 4; ++mi)
#pragma unroll
    for (int ni = 0; ni < 4; ++ni)
      acc[mi][ni] = (f32x4)0.0f;

  const unsigned short* Ab = A + (size_t)bm * DDIM;
  const unsigned short* Bb = B + (size_t)(jBase + bn) * DDIM;
  const int stRow  = lane >> 2;
  const int stColH = (lane & 3) * 8;

  for (int kt = 0; kt < DDIM / 32; ++kt) {
#pragma unroll
    for (int p = 0; p < 2; ++p) {
      const int off = (p * 4 + wave) * 1024;
      const int r0  = off >> 6;
      gload_lds16(Ab + (size_t)(r0 + stRow) * DDIM + kt * 32 + stColH, (char*)lA + off);
      gload_lds16(Bb + (size_t)(r0 + stRow) * DDIM + kt * 32 + stColH, (char*)lB + off);
    }
    __syncthreads();

    bf16x8 af[4], bfr[4];
#pragma unroll
    for (int mi = 0; mi < 4; ++mi) {
      const int r = wm + mi * 16 + (lane & 15);
      af[mi] = *(const bf16x8*)((const char*)lA + r * 64 + (lane >> 4) * 16);
    }
#pragma unroll
    for (int ni = 0; ni < 4; ++ni) {
      const int r = wn + ni * 16 + (lane & 15);
      bfr[ni] = *(const bf16x8*)((const char*)lB + r * 64 + (lane >> 4) * 16);
    }
#pragma unroll
    for (int mi = 0; mi < 4; ++mi)
#pragma unroll
      for (int ni = 0; ni < 4; ++ni)
        acc[mi][ni] = __builtin_amdgcn_mfma_f32_16x16x32_bf16(af[mi], bfr[ni], acc[mi][ni], 0, 0, 0);
    __syncthreads();
  }

  if (STORE_SQ == 0) {
#pragma unroll
    for (int mi = 0; mi < 4; ++mi) {
#pragma unroll
      for (int j = 0; j < 4; ++j) {
        const int i = bm + wm + mi * 16 + ((lane >> 4) << 2) + j;
        const float av = a2[i];
        float mn = __builtin_inff();
#pragma unroll
        for (int ni = 0; ni < 4; ++ni) {
          const int jj = bn + wn + ni * 16 + (lane & 15);
          mn = fminf(mn, av + b2[jj] - 2.0f * acc[mi][ni][j]);
        }
#pragma unroll
        for (int s = 1; s < 16; s <<= 1) mn = fminf(mn, __shfl_xor(mn, s));
        if ((lane & 15) == 0) atomicMin(&rowMin[i], __float_as_uint(fmaxf(mn, 0.0f)));
      }
    }
  } else {
#pragma unroll
    for (int mi = 0; mi < 4; ++mi) {
#pragma unroll
      for (int j = 0; j < 4; ++j) {
        const int i = bm + wm + mi * 16 + ((lane >> 4) << 2) + j;
        const float av = a2[i];
#pragma unroll
        for (int ni = 0; ni < 4; ++ni) {
          const int jj = bn + wn + ni * 16 + (lane & 15);
          sqbuf[(size_t)i * chunkCols + jj] = av + b2[jBase + jj] - 2.0f * acc[mi][ni][j];
        }
      }
    }
  }
}

// ---------------- exact top-30 per row (fallback; flag-gated) ---------------
template<int VPL>
__global__ __launch_bounds__(64) void select_kernel(
    const float* __restrict__ sqbuf, const int* __restrict__ flag,
    float* __restrict__ tv, int* __restrict__ ti, int jBase, int isFirst)
{
  if (*flag == 0) return;
  const int row = blockIdx.x, lane = threadIdx.x;
  const int CH = VPL * 64;
  float v[VPL];
#pragma unroll
  for (int q = 0; q < VPL; ++q)
    v[q] = sqbuf[(size_t)row * CH + q * 64 + lane];
  float cv; int ci;
  if (isFirst) { cv = __builtin_inff(); ci = 0x7fffffff; }
  else {
    cv = (lane < NQ) ? tv[row * 32 + lane] : __builtin_inff();
    ci = (lane < NQ) ? ti[row * 32 + lane] : 0x7fffffff;
  }
  for (int k = 0; k < NQ; ++k) {
    float mv = cv; int mi_ = ci;
#pragma unroll
    for (int q = 0; q < VPL; ++q) {
      const int col = jBase + q * 64 + lane;
      const bool b = (v[q] < mv) || (v[q] == mv && col < mi_);
      mv  = b ? v[q] : mv;
      mi_ = b ? col  : mi_;
    }
#pragma unroll
    for (int s = 1; s < 64; s <<= 1) {
      const float ov = __shfl_xor(mv, s);
      const int   oi = __shfl_xor(mi_, s);
      const bool b = (ov < mv) || (ov == mv && oi < mi_);
      mv  = b ? ov : mv;
      mi_ = b ? oi : mi_;
    }
    if (mi_ == ci) cv = __builtin_inff();
    else if (mi_ >= jBase) {
      const int rel = mi_ - jBase;
      if ((rel & 63) == lane) {
        const int lq = rel >> 6;
#pragma unroll
        for (int q = 0; q < VPL; ++q) if (q == lq) v[q] = __builtin_inff();
      }
    }
    if (lane == 0) { tv[row * 32 + k] = mv; ti[row * 32 + k] = mi_; }
  }
}

// ---------------- final reduction ------------------------------------------
__global__ __launch_bounds__(256) void final_kernel(
    const float* __restrict__ posr, const float* __restrict__ tv,
    const int* __restrict__ ti, const int* __restrict__ rn,
    const int* __restrict__ flag, float* __restrict__ out)
{
  const int t = threadIdx.x;
  const int useNeg = (*flag != 0);
  double ps = 0.0, ns = 0.0;
  for (int r = t; r < NROWS; r += 256) {
    ps += (double)posr[r];
    if (useNeg) {
      int k = rn[r];
      const int sel = ti[r * 32 + k];
      if (sel == r) k = (k + 1) % NQ;
      const float d = sqrtf(fmaxf(tv[r * 32 + k], 0.0f));
      ns += (double)fmaxf(MARGINF - d, 0.0f);
    }
  }
  __shared__ double sp[256], sn[256];
  sp[t] = ps; sn[t] = ns;
  __syncthreads();
  for (int s = 128; s > 0; s >>= 1) {
    if (t < s) { sp[t] += sp[t + s]; sn[t] += sn[t + s]; }
    __syncthreads();
  }
  if (t == 0) out[0] = (float)(sp[0] / NROWS + sn[0] / NROWS);
}

extern "C" void kernel_launch(void* const* d_in, const int* in_sizes, int n_in,
                              void* d_out, int out_size, void* d_ws, size_t ws_size,
                              hipStream_t stream) {
  (void)in_sizes; (void)n_in; (void)out_size;
  const float* o1 = (const float*)d_in[0];
  const float* o2 = (const float*)d_in[1];
  const int*   rn = (const int*)d_in[2];
  float* out = (float*)d_out;

  char* ws = (char*)d_ws;
  size_t off = 0;
  auto alloc = [&](size_t b) { void* p = ws + off; off += (b + 255) & ~(size_t)255; return p; };
  unsigned short* o1b = (unsigned short*)alloc((size_t)NROWS * DDIM * 2);  // 16 MB
  unsigned short* o2b = (unsigned short*)alloc((size_t)NROWS * DDIM * 2);  // 16 MB (contiguous after o1b)
  float* a2   = (float*)alloc((size_t)NROWS * 4);
  float* b2   = (float*)alloc((size_t)NROWS * 4);
  float* posr = (float*)alloc((size_t)NROWS * 4);
  unsigned int* rowMin = (unsigned int*)alloc((size_t)NROWS * 4);
  int*   flag = (int*)alloc(256);
  float* tv   = (float*)alloc((size_t)NROWS * 32 * 4);
  int*   ti   = (int*)alloc((size_t)NROWS * 32 * 4);
  unsigned short* proj = (unsigned short*)alloc((size_t)2 * NROWS * NPROJ * 2);  // 2 MB
  float* pnorm = (float*)alloc((size_t)2 * NROWS * 4);                           // 128 KB
  const size_t remain = ws_size > off ? ws_size - off : 0;
  int chunk;
  if      (remain >= (size_t)NROWS * 8192 * 4) chunk = 8192;
  else if (remain >= (size_t)NROWS * 2048 * 4) chunk = 2048;
  else if (remain >= (size_t)NROWS * 512 * 4)  chunk = 512;
  else                                         chunk = 128;
  float* sqbuf = (float*)(ws + off);

  prep_kernel<<<NROWS, 256, 0, stream>>>(o1, o2, o1b, o2b, a2, b2, posr, rowMin, flag);
  proj_kernel<<<2 * NROWS / 64, 256, 0, stream>>>(o1b, proj, pnorm);
  gram64_kernel<<<dim3(64, 8), 512, 0, stream>>>(proj, pnorm, rowMin);
  flag_kernel<<<dim3(NROWS / 256), 256, 0, stream>>>(rowMin, flag);

  const int nch = NROWS / chunk;
  for (int c = 0; c < nch; ++c) {
    gemm_kernel<1><<<dim3(chunk / 128, 64), 256, 0, stream>>>(o1b, o2b, a2, b2, rowMin, flag,
                                                              sqbuf, c * chunk, chunk);
    const int first = (c == 0);
    if      (chunk == 8192) select_kernel<128><<<NROWS, 64, 0, stream>>>(sqbuf, flag, tv, ti, c * chunk, first);
    else if (chunk == 2048) select_kernel<32><<<NROWS, 64, 0, stream>>>(sqbuf, flag, tv, ti, c * chunk, first);
    else if (chunk == 512)  select_kernel<8><<<NROWS, 64, 0, stream>>>(sqbuf, flag, tv, ti, c * chunk, first);
    else                    select_kernel<2><<<NROWS, 64, 0, stream>>>(sqbuf, flag, tv, ti, c * chunk, first);
  }
  final_kernel<<<1, 256, 0, stream>>>(posr, tv, ti, rn, flag, out);
}

// Round 11
// 72.144 us; speedup vs baseline: 1.9689x; 1.1692x over previous
//
#include <hip/hip_runtime.h>
#include <hip/hip_bf16.h>
#include <stdint.h>

#define NROWS 8192
#define DDIM  1024
#define NQ    30
#define MARGINF 2.0f
#define NPROJ 64

typedef __attribute__((ext_vector_type(8))) short bf16x8;   // 8 bf16 (4 VGPRs)
typedef __attribute__((ext_vector_type(4))) float f32x4;    // MFMA accum

static __device__ __forceinline__ unsigned short f2bf(float f) {
  union { float f; unsigned u; } c; c.f = f;
  return (unsigned short)((c.u + 0x7fffu + ((c.u >> 16) & 1u)) >> 16);  // RNE
}

static __device__ __forceinline__ void gload_lds16(const void* g, void* l) {
  __builtin_amdgcn_global_load_lds(
      (const __attribute__((address_space(1))) void*)g,
      (__attribute__((address_space(3))) void*)l, 16, 0, 0);
}

// ============================================================================
// prep2: single pass over fp32 inputs. Computes per row:
//  - posr (pos term), a2/b2 (norms, fallback-only)
//  - proj (64 Hadamard projections, ±1/32 columns) via BUCKET SUMS + FHT-64:
//      proj[p] = (1/32) * sum_r (-1)^popc(p&r) * S[r],  S[r] = sum_{k%64==r} x[k]
//    (p&k touches only k's low 6 bits -> exact factorization; fp32, more
//    accurate than the old bf16-MFMA proj_kernel it replaces)
//  - pnorm from the BF16-ROUNDED proj (so gram64's pnA+pnB-2*gram bound is
//    consistent with the stored operands)
// No bf16 X cast here (moved to flag-gated cast_kernel): 96->66 MB traffic.
// ============================================================================
__global__ __launch_bounds__(256) void prep2_kernel(
    const float* __restrict__ o1, const float* __restrict__ o2,
    float* __restrict__ a2, float* __restrict__ b2, float* __restrict__ posr,
    unsigned short* __restrict__ proj, float* __restrict__ pnorm,
    unsigned int* __restrict__ rowMin, int* __restrict__ flag)
{
  const int row = blockIdx.x;
  const int t = threadIdx.x;
  const int lane = t & 63;
  const int wv = t >> 6;
  const float4 x1 = ((const float4*)(o1 + (size_t)row * DDIM))[t];
  const float4 x2 = ((const float4*)(o2 + (size_t)row * DDIM))[t];

  // ---- norms + pos ----
  float s1 = x1.x*x1.x + x1.y*x1.y + x1.z*x1.z + x1.w*x1.w;
  float s2 = x2.x*x2.x + x2.y*x2.y + x2.z*x2.z + x2.w*x2.w;
  float d0 = x2.x-x1.x, d1 = x2.y-x1.y, d2 = x2.z-x1.z, d3 = x2.w-x1.w;
  float sp = d0*d0 + d1*d1 + d2*d2 + d3*d3;
  for (int s = 1; s < 64; s <<= 1) {
    s1 += __shfl_xor(s1, s);
    s2 += __shfl_xor(s2, s);
    sp += __shfl_xor(sp, s);
  }
  __shared__ float r1[4], r2[4], rp[4];
  if (lane == 0) { r1[wv] = s1; r2[wv] = s2; rp[wv] = sp; }

  // ---- bucket sums: element k=4t+i -> bucket 4*(t&15)+i ----
  __shared__ float S1[4][64], S2[4][64];
  float p1v[4] = {x1.x, x1.y, x1.z, x1.w};
  float p2v[4] = {x2.x, x2.y, x2.z, x2.w};
#pragma unroll
  for (int i = 0; i < 4; ++i) {
    p1v[i] += __shfl_xor(p1v[i], 16); p1v[i] += __shfl_xor(p1v[i], 32);
    p2v[i] += __shfl_xor(p2v[i], 16); p2v[i] += __shfl_xor(p2v[i], 32);
  }
  if (lane < 16) {
#pragma unroll
    for (int i = 0; i < 4; ++i) {
      S1[wv][lane * 4 + i] = p1v[i];
      S2[wv][lane * 4 + i] = p2v[i];
    }
  }
  __syncthreads();

  if (t == 0) {
    a2[row]   = r1[0] + r1[1] + r1[2] + r1[3];
    b2[row]   = r2[0] + r2[1] + r2[2] + r2[3];
    posr[row] = rp[0] + rp[1] + rp[2] + rp[3];
    if (row == 0) { rowMin[0] = 0x7F800000u; *flag = 0; }
  }

  // ---- FHT-64 (waves 0,1 handle o1,o2) ----
  if (wv < 2) {
    const float* Sm = (wv == 0) ? &S1[0][0] : &S2[0][0];
    float v = Sm[lane] + Sm[64 + lane] + Sm[128 + lane] + Sm[192 + lane];
#pragma unroll
    for (int s = 1; s < 64; s <<= 1) {
      const float p = __shfl_xor(v, s);
      v = (lane & s) ? (p - v) : (v + p);
    }
    v *= 0.03125f;                               // 1/32 column scale
    const unsigned short ub = f2bf(v);
    union { unsigned u; float f; } cb; cb.u = ((unsigned)ub) << 16;
    const float vb = cb.f;                       // bf16-rounded value
    const size_t prow = (wv == 0) ? (size_t)row : (size_t)NROWS + row;
    proj[prow * NPROJ + lane] = ub;
    float sq = vb * vb;
#pragma unroll
    for (int s = 1; s < 64; s <<= 1) sq += __shfl_xor(sq, s);
    if (lane == 0) pnorm[prow] = sq;
  }
}

// ============================================================================
// K=64 gram of projections -> GLOBAL min of the certified lower bound.
// (R10-validated: 512 blocks x 8 waves, wave tile 64x32, FETCH 5.8 MB fully
// L2-absorbed; LDS block reduce -> ONE atomicMin per block.)
// ============================================================================
__global__ __launch_bounds__(512, 3) void gram64_kernel(
    const unsigned short* __restrict__ P,   // proj: 16384 x 64 bf16
    const float* __restrict__ pn,           // 16384
    unsigned int* __restrict__ rowMin)
{
  __shared__ float sred[8];
  const int tid  = threadIdx.x;
  const int lane = tid & 63;
  const int wave = tid >> 6;
  const int wr = wave >> 2;
  const int wc = wave & 3;
  const int bm = blockIdx.x * 128;
  const int bg = blockIdx.y * 1024;
  const int rlane = lane & 15;
  const int c32   = lane >> 4;

  bf16x8 af[4][2];
#pragma unroll
  for (int mi = 0; mi < 4; ++mi)
#pragma unroll
    for (int ks = 0; ks < 2; ++ks)
      af[mi][ks] = *(const bf16x8*)(
          P + (size_t)(bm + wr * 64 + mi * 16 + rlane) * NPROJ + ks * 32 + c32 * 8);

  float rmn[4][4];
#pragma unroll
  for (int mi = 0; mi < 4; ++mi)
#pragma unroll
    for (int j = 0; j < 4; ++j) rmn[mi][j] = __builtin_inff();

#define LOADB(buf, pnv, t) do { \
    const int bn_ = bg + (t) * 128 + wc * 32; \
    _Pragma("unroll") for (int ni = 0; ni < 2; ++ni) { \
      _Pragma("unroll") for (int ks = 0; ks < 2; ++ks) \
        buf[ni][ks] = *(const bf16x8*)( \
            P + (size_t)(NROWS + bn_ + ni * 16 + rlane) * NPROJ + ks * 32 + c32 * 8); \
      pnv[ni] = pn[NROWS + bn_ + ni * 16 + rlane]; \
    } \
  } while (0)

#define COMPUTE(buf, pnv) do { \
    f32x4 acc[4][2]; \
    _Pragma("unroll") for (int mi = 0; mi < 4; ++mi) \
    _Pragma("unroll") for (int ni = 0; ni < 2; ++ni) acc[mi][ni] = (f32x4)0.0f; \
    _Pragma("unroll") for (int mi = 0; mi < 4; ++mi) \
    _Pragma("unroll") for (int ni = 0; ni < 2; ++ni) \
    _Pragma("unroll") for (int ks = 0; ks < 2; ++ks) \
      acc[mi][ni] = __builtin_amdgcn_mfma_f32_16x16x32_bf16( \
          af[mi][ks], buf[ni][ks], acc[mi][ni], 0, 0, 0); \
    _Pragma("unroll") for (int mi = 0; mi < 4; ++mi) \
    _Pragma("unroll") for (int j = 0; j < 4; ++j) \
    _Pragma("unroll") for (int ni = 0; ni < 2; ++ni) \
      rmn[mi][j] = fminf(rmn[mi][j], pnv[ni] - 2.0f * acc[mi][ni][j]); \
  } while (0)

  bf16x8 bA[2][2], bB[2][2];
  float pA[2], pB[2];
  LOADB(bA, pA, 0);
#pragma unroll
  for (int t = 0; t < 8; t += 2) {
    LOADB(bB, pB, t + 1);
    COMPUTE(bA, pA);
    if (t + 2 < 8) LOADB(bA, pA, t + 2);
    COMPUTE(bB, pB);
  }
#undef LOADB
#undef COMPUTE

  float tot = __builtin_inff();
#pragma unroll
  for (int mi = 0; mi < 4; ++mi) {
#pragma unroll
    for (int j = 0; j < 4; ++j) {
      const int row = bm + wr * 64 + mi * 16 + (c32 << 2) + j;
      tot = fminf(tot, rmn[mi][j] + pn[row]);
    }
  }
#pragma unroll
  for (int s = 1; s < 64; s <<= 1) tot = fminf(tot, __shfl_xor(tot, s));
  if (lane == 0) sred[wave] = tot;
  __syncthreads();
  if (tid == 0) {
    float m = sred[0];
#pragma unroll
    for (int w = 1; w < 8; ++w) m = fminf(m, sred[w]);
    atomicMin(&rowMin[0], __float_as_uint(fmaxf(m, 0.0f)));
  }
}

// ---------------- flag: lower-bound min < 16 (dist < 4)? 1 block ------------
__global__ __launch_bounds__(64) void flag_kernel(const unsigned int* __restrict__ rowMin,
                                                  int* __restrict__ flag)
{
  if (threadIdx.x == 0 && rowMin[0] < 0x41800000u /* bits(16.0f) */) *flag = 1;
}

// ---------------- cast (flag-gated): fp32 -> bf16 for the exact fallback ----
__global__ __launch_bounds__(256) void cast_kernel(
    const float* __restrict__ o1, const float* __restrict__ o2,
    unsigned short* __restrict__ o1b, unsigned short* __restrict__ o2b,
    const int* __restrict__ flag)
{
  if (*flag == 0) return;
  const int row = blockIdx.x;
  const int t = threadIdx.x;
  const float4 x1 = ((const float4*)(o1 + (size_t)row * DDIM))[t];
  const float4 x2 = ((const float4*)(o2 + (size_t)row * DDIM))[t];
  *(ushort4*)(o1b + (size_t)row * DDIM + t * 4) =
      make_ushort4(f2bf(x1.x), f2bf(x1.y), f2bf(x1.z), f2bf(x1.w));
  *(ushort4*)(o2b + (size_t)row * DDIM + t * 4) =
      make_ushort4(f2bf(x2.x), f2bf(x2.y), f2bf(x2.z), f2bf(x2.w));
}

// ---------------- 128^2 bf16 GEMM (flag-gated exact-path sq store) ----------
__global__ __launch_bounds__(256) void gemm_kernel(
    const unsigned short* __restrict__ A, const unsigned short* __restrict__ B,
    const float* __restrict__ a2, const float* __restrict__ b2,
    const int* __restrict__ flag,
    float* __restrict__ sqbuf, int jBase, int chunkCols)
{
  if (*flag == 0) return;                     // never taken on benign data
  __shared__ __align__(16) unsigned short lA[128 * 32];
  __shared__ __align__(16) unsigned short lB[128 * 32];
  const int tid  = threadIdx.x;
  const int lane = tid & 63;
  const int wave = tid >> 6;
  const int bm = blockIdx.y * 128;
  const int bn = blockIdx.x * 128;
  const int wm = (wave >> 1) * 64;
  const int wn = (wave & 1) * 64;

  f32x4 acc[4][4];
#pragma unroll
  for (int mi = 0; mi < 4; ++mi)
#pragma unroll
    for (int ni = 0; ni < 4; ++ni)
      acc[mi][ni] = (f32x4)0.0f;

  const unsigned short* Ab = A + (size_t)bm * DDIM;
  const unsigned short* Bb = B + (size_t)(jBase + bn) * DDIM;
  const int stRow  = lane >> 2;
  const int stColH = (lane & 3) * 8;

  for (int kt = 0; kt < DDIM / 32; ++kt) {
#pragma unroll
    for (int p = 0; p < 2; ++p) {
      const int off = (p * 4 + wave) * 1024;
      const int r0  = off >> 6;
      gload_lds16(Ab + (size_t)(r0 + stRow) * DDIM + kt * 32 + stColH, (char*)lA + off);
      gload_lds16(Bb + (size_t)(r0 + stRow) * DDIM + kt * 32 + stColH, (char*)lB + off);
    }
    __syncthreads();

    bf16x8 af[4], bfr[4];
#pragma unroll
    for (int mi = 0; mi < 4; ++mi) {
      const int r = wm + mi * 16 + (lane & 15);
      af[mi] = *(const bf16x8*)((const char*)lA + r * 64 + (lane >> 4) * 16);
    }
#pragma unroll
    for (int ni = 0; ni < 4; ++ni) {
      const int r = wn + ni * 16 + (lane & 15);
      bfr[ni] = *(const bf16x8*)((const char*)lB + r * 64 + (lane >> 4) * 16);
    }
#pragma unroll
    for (int mi = 0; mi < 4; ++mi)
#pragma unroll
      for (int ni = 0; ni < 4; ++ni)
        acc[mi][ni] = __builtin_amdgcn_mfma_f32_16x16x32_bf16(af[mi], bfr[ni], acc[mi][ni], 0, 0, 0);
    __syncthreads();
  }

#pragma unroll
  for (int mi = 0; mi < 4; ++mi) {
#pragma unroll
    for (int j = 0; j < 4; ++j) {
      const int i = bm + wm + mi * 16 + ((lane >> 4) << 2) + j;
      const float av = a2[i];
#pragma unroll
      for (int ni = 0; ni < 4; ++ni) {
        const int jj = bn + wn + ni * 16 + (lane & 15);
        sqbuf[(size_t)i * chunkCols + jj] = av + b2[jBase + jj] - 2.0f * acc[mi][ni][j];
      }
    }
  }
}

// ---------------- exact top-30 per row (fallback; flag-gated) ---------------
template<int VPL>
__global__ __launch_bounds__(64) void select_kernel(
    const float* __restrict__ sqbuf, const int* __restrict__ flag,
    float* __restrict__ tv, int* __restrict__ ti, int jBase, int isFirst)
{
  if (*flag == 0) return;
  const int row = blockIdx.x, lane = threadIdx.x;
  const int CH = VPL * 64;
  float v[VPL];
#pragma unroll
  for (int q = 0; q < VPL; ++q)
    v[q] = sqbuf[(size_t)row * CH + q * 64 + lane];
  float cv; int ci;
  if (isFirst) { cv = __builtin_inff(); ci = 0x7fffffff; }
  else {
    cv = (lane < NQ) ? tv[row * 32 + lane] : __builtin_inff();
    ci = (lane < NQ) ? ti[row * 32 + lane] : 0x7fffffff;
  }
  for (int k = 0; k < NQ; ++k) {
    float mv = cv; int mi_ = ci;
#pragma unroll
    for (int q = 0; q < VPL; ++q) {
      const int col = jBase + q * 64 + lane;
      const bool b = (v[q] < mv) || (v[q] == mv && col < mi_);
      mv  = b ? v[q] : mv;
      mi_ = b ? col  : mi_;
    }
#pragma unroll
    for (int s = 1; s < 64; s <<= 1) {
      const float ov = __shfl_xor(mv, s);
      const int   oi = __shfl_xor(mi_, s);
      const bool b = (ov < mv) || (ov == mv && oi < mi_);
      mv  = b ? ov : mv;
      mi_ = b ? oi : mi_;
    }
    if (mi_ == ci) cv = __builtin_inff();
    else if (mi_ >= jBase) {
      const int rel = mi_ - jBase;
      if ((rel & 63) == lane) {
        const int lq = rel >> 6;
#pragma unroll
        for (int q = 0; q < VPL; ++q) if (q == lq) v[q] = __builtin_inff();
      }
    }
    if (lane == 0) { tv[row * 32 + k] = mv; ti[row * 32 + k] = mi_; }
  }
}

// ---------------- final reduction ------------------------------------------
__global__ __launch_bounds__(256) void final_kernel(
    const float* __restrict__ posr, const float* __restrict__ tv,
    const int* __restrict__ ti, const int* __restrict__ rn,
    const int* __restrict__ flag, float* __restrict__ out)
{
  const int t = threadIdx.x;
  const int useNeg = (*flag != 0);
  double ps = 0.0, ns = 0.0;
  for (int r = t; r < NROWS; r += 256) {
    ps += (double)posr[r];
    if (useNeg) {
      int k = rn[r];
      const int sel = ti[r * 32 + k];
      if (sel == r) k = (k + 1) % NQ;
      const float d = sqrtf(fmaxf(tv[r * 32 + k], 0.0f));
      ns += (double)fmaxf(MARGINF - d, 0.0f);
    }
  }
  __shared__ double sp[256], sn[256];
  sp[t] = ps; sn[t] = ns;
  __syncthreads();
  for (int s = 128; s > 0; s >>= 1) {
    if (t < s) { sp[t] += sp[t + s]; sn[t] += sn[t + s]; }
    __syncthreads();
  }
  if (t == 0) out[0] = (float)(sp[0] / NROWS + sn[0] / NROWS);
}

extern "C" void kernel_launch(void* const* d_in, const int* in_sizes, int n_in,
                              void* d_out, int out_size, void* d_ws, size_t ws_size,
                              hipStream_t stream) {
  (void)in_sizes; (void)n_in; (void)out_size;
  const float* o1 = (const float*)d_in[0];
  const float* o2 = (const float*)d_in[1];
  const int*   rn = (const int*)d_in[2];
  float* out = (float*)d_out;

  char* ws = (char*)d_ws;
  size_t off = 0;
  auto alloc = [&](size_t b) { void* p = ws + off; off += (b + 255) & ~(size_t)255; return p; };
  unsigned short* o1b = (unsigned short*)alloc((size_t)NROWS * DDIM * 2);  // 16 MB (fallback only)
  unsigned short* o2b = (unsigned short*)alloc((size_t)NROWS * DDIM * 2);  // 16 MB (fallback only)
  float* a2   = (float*)alloc((size_t)NROWS * 4);
  float* b2   = (float*)alloc((size_t)NROWS * 4);
  float* posr = (float*)alloc((size_t)NROWS * 4);
  unsigned int* rowMin = (unsigned int*)alloc(256);
  int*   flag = (int*)alloc(256);
  float* tv   = (float*)alloc((size_t)NROWS * 32 * 4);
  int*   ti   = (int*)alloc((size_t)NROWS * 32 * 4);
  unsigned short* proj = (unsigned short*)alloc((size_t)2 * NROWS * NPROJ * 2);  // 2 MB
  float* pnorm = (float*)alloc((size_t)2 * NROWS * 4);                           // 128 KB
  const size_t remain = ws_size > off ? ws_size - off : 0;
  int chunk;
  if      (remain >= (size_t)NROWS * 8192 * 4) chunk = 8192;
  else if (remain >= (size_t)NROWS * 4096 * 4) chunk = 4096;
  else if (remain >= (size_t)NROWS * 2048 * 4) chunk = 2048;
  else if (remain >= (size_t)NROWS * 512 * 4)  chunk = 512;
  else                                         chunk = 128;
  float* sqbuf = (float*)(ws + off);

  prep2_kernel<<<NROWS, 256, 0, stream>>>(o1, o2, a2, b2, posr, proj, pnorm, rowMin, flag);
  gram64_kernel<<<dim3(64, 8), 512, 0, stream>>>(proj, pnorm, rowMin);
  flag_kernel<<<1, 64, 0, stream>>>(rowMin, flag);

  // Fallback chain (all flag-gated; never taken on benign data, proven R5).
  cast_kernel<<<NROWS, 256, 0, stream>>>(o1, o2, o1b, o2b, flag);
  const int nch = NROWS / chunk;
  for (int c = 0; c < nch; ++c) {
    gemm_kernel<<<dim3(chunk / 128, 64), 256, 0, stream>>>(o1b, o2b, a2, b2, flag,
                                                           sqbuf, c * chunk, chunk);
    const int first = (c == 0);
    if      (chunk == 8192) select_kernel<128><<<NROWS, 64, 0, stream>>>(sqbuf, flag, tv, ti, c * chunk, first);
    else if (chunk == 4096) select_kernel<64><<<NROWS, 64, 0, stream>>>(sqbuf, flag, tv, ti, c * chunk, first);
    else if (chunk == 2048) select_kernel<32><<<NROWS, 64, 0, stream>>>(sqbuf, flag, tv, ti, c * chunk, first);
    else if (chunk == 512)  select_kernel<8><<<NROWS, 64, 0, stream>>>(sqbuf, flag, tv, ti, c * chunk, first);
    else                    select_kernel<2><<<NROWS, 64, 0, stream>>>(sqbuf, flag, tv, ti, c * chunk, first);
  }
  final_kernel<<<1, 256, 0, stream>>>(posr, tv, ti, rn, flag, out);
}

// Round 12
// 63.347 us; speedup vs baseline: 2.2423x; 1.1389x over previous
//
#include <hip/hip_runtime.h>
#include <hip/hip_bf16.h>
#include <stdint.h>

#define NROWS 8192
#define DDIM  1024
#define NQ    30
#define MARGINF 2.0f
#define NPROJ 64

typedef __attribute__((ext_vector_type(8))) short bf16x8;   // 8 bf16 (4 VGPRs)
typedef __attribute__((ext_vector_type(4))) float f32x4;    // MFMA accum

static __device__ __forceinline__ unsigned short f2bf(float f) {
  union { float f; unsigned u; } c; c.f = f;
  return (unsigned short)((c.u + 0x7fffu + ((c.u >> 16) & 1u)) >> 16);  // RNE
}

static __device__ __forceinline__ float bf2f(unsigned short b) {
  union { unsigned u; float f; } c; c.u = ((unsigned)b) << 16;
  return c.f;
}

static __device__ __forceinline__ void gload_lds16(const void* g, void* l) {
  __builtin_amdgcn_global_load_lds(
      (const __attribute__((address_space(1))) void*)g,
      (__attribute__((address_space(3))) void*)l, 16, 0, 0);
}

// ============================================================================
// prep2: single pass over fp32 inputs. Per row: posr, a2/b2 (fallback-only),
// proj (64 Hadamard projections, ±1/32 cols) via bucket sums + in-register
// FHT-64, pnorm from the BF16-ROUNDED proj (keeps gram64's bound consistent).
// ============================================================================
__global__ __launch_bounds__(256) void prep2_kernel(
    const float* __restrict__ o1, const float* __restrict__ o2,
    float* __restrict__ a2, float* __restrict__ b2, float* __restrict__ posr,
    unsigned short* __restrict__ proj, float* __restrict__ pnorm)
{
  const int row = blockIdx.x;
  const int t = threadIdx.x;
  const int lane = t & 63;
  const int wv = t >> 6;
  const float4 x1 = ((const float4*)(o1 + (size_t)row * DDIM))[t];
  const float4 x2 = ((const float4*)(o2 + (size_t)row * DDIM))[t];

  // ---- norms + pos ----
  float s1 = x1.x*x1.x + x1.y*x1.y + x1.z*x1.z + x1.w*x1.w;
  float s2 = x2.x*x2.x + x2.y*x2.y + x2.z*x2.z + x2.w*x2.w;
  float d0 = x2.x-x1.x, d1 = x2.y-x1.y, d2 = x2.z-x1.z, d3 = x2.w-x1.w;
  float sp = d0*d0 + d1*d1 + d2*d2 + d3*d3;
  for (int s = 1; s < 64; s <<= 1) {
    s1 += __shfl_xor(s1, s);
    s2 += __shfl_xor(s2, s);
    sp += __shfl_xor(sp, s);
  }
  __shared__ float r1[4], r2[4], rp[4];
  if (lane == 0) { r1[wv] = s1; r2[wv] = s2; rp[wv] = sp; }

  // ---- bucket sums: element k=4t+i -> bucket 4*(t&15)+i ----
  __shared__ float S1[4][64], S2[4][64];
  float p1v[4] = {x1.x, x1.y, x1.z, x1.w};
  float p2v[4] = {x2.x, x2.y, x2.z, x2.w};
#pragma unroll
  for (int i = 0; i < 4; ++i) {
    p1v[i] += __shfl_xor(p1v[i], 16); p1v[i] += __shfl_xor(p1v[i], 32);
    p2v[i] += __shfl_xor(p2v[i], 16); p2v[i] += __shfl_xor(p2v[i], 32);
  }
  if (lane < 16) {
#pragma unroll
    for (int i = 0; i < 4; ++i) {
      S1[wv][lane * 4 + i] = p1v[i];
      S2[wv][lane * 4 + i] = p2v[i];
    }
  }
  __syncthreads();

  if (t == 0) {
    a2[row]   = r1[0] + r1[1] + r1[2] + r1[3];
    b2[row]   = r2[0] + r2[1] + r2[2] + r2[3];
    posr[row] = rp[0] + rp[1] + rp[2] + rp[3];
  }

  // ---- FHT-64 (waves 0,1 handle o1,o2) ----
  if (wv < 2) {
    const float* Sm = (wv == 0) ? &S1[0][0] : &S2[0][0];
    float v = Sm[lane] + Sm[64 + lane] + Sm[128 + lane] + Sm[192 + lane];
#pragma unroll
    for (int s = 1; s < 64; s <<= 1) {
      const float p = __shfl_xor(v, s);
      v = (lane & s) ? (p - v) : (v + p);
    }
    v *= 0.03125f;                               // 1/32 column scale
    const unsigned short ub = f2bf(v);
    const float vb = bf2f(ub);                   // bf16-rounded value
    const size_t prow = (wv == 0) ? (size_t)row : (size_t)NROWS + row;
    proj[prow * NPROJ + lane] = ub;
    float sq = vb * vb;
#pragma unroll
    for (int s = 1; s < 64; s <<= 1) sq += __shfl_xor(sq, s);
    if (lane == 0) pnorm[prow] = sq;
  }
}

// ============================================================================
// K=64 gram of projections -> per-block min of the certified lower bound,
// written to blockmins[bid] (NO atomics — R9/R11 lesson: same-address
// atomicMin serializes ~35cyc each; 512 of them = ~7us hidden cost).
// Compute structure is R10-validated (512 blocks x 8 waves, 64x32 wave tile,
// FETCH 5.8 MB fully L2-absorbed).
// ============================================================================
__global__ __launch_bounds__(512, 3) void gram64_kernel(
    const unsigned short* __restrict__ P,   // proj: 16384 x 64 bf16
    const float* __restrict__ pn,           // 16384
    float* __restrict__ blockmins)          // 512
{
  __shared__ float sred[8];
  const int tid  = threadIdx.x;
  const int lane = tid & 63;
  const int wave = tid >> 6;
  const int wr = wave >> 2;
  const int wc = wave & 3;
  const int bm = blockIdx.x * 128;
  const int bg = blockIdx.y * 1024;
  const int rlane = lane & 15;
  const int c32   = lane >> 4;

  bf16x8 af[4][2];
#pragma unroll
  for (int mi = 0; mi < 4; ++mi)
#pragma unroll
    for (int ks = 0; ks < 2; ++ks)
      af[mi][ks] = *(const bf16x8*)(
          P + (size_t)(bm + wr * 64 + mi * 16 + rlane) * NPROJ + ks * 32 + c32 * 8);

  float rmn[4][4];
#pragma unroll
  for (int mi = 0; mi < 4; ++mi)
#pragma unroll
    for (int j = 0; j < 4; ++j) rmn[mi][j] = __builtin_inff();

#define LOADB(buf, pnv, t) do { \
    const int bn_ = bg + (t) * 128 + wc * 32; \
    _Pragma("unroll") for (int ni = 0; ni < 2; ++ni) { \
      _Pragma("unroll") for (int ks = 0; ks < 2; ++ks) \
        buf[ni][ks] = *(const bf16x8*)( \
            P + (size_t)(NROWS + bn_ + ni * 16 + rlane) * NPROJ + ks * 32 + c32 * 8); \
      pnv[ni] = pn[NROWS + bn_ + ni * 16 + rlane]; \
    } \
  } while (0)

#define COMPUTE(buf, pnv) do { \
    f32x4 acc[4][2]; \
    _Pragma("unroll") for (int mi = 0; mi < 4; ++mi) \
    _Pragma("unroll") for (int ni = 0; ni < 2; ++ni) acc[mi][ni] = (f32x4)0.0f; \
    _Pragma("unroll") for (int mi = 0; mi < 4; ++mi) \
    _Pragma("unroll") for (int ni = 0; ni < 2; ++ni) \
    _Pragma("unroll") for (int ks = 0; ks < 2; ++ks) \
      acc[mi][ni] = __builtin_amdgcn_mfma_f32_16x16x32_bf16( \
          af[mi][ks], buf[ni][ks], acc[mi][ni], 0, 0, 0); \
    _Pragma("unroll") for (int mi = 0; mi < 4; ++mi) \
    _Pragma("unroll") for (int j = 0; j < 4; ++j) \
    _Pragma("unroll") for (int ni = 0; ni < 2; ++ni) \
      rmn[mi][j] = fminf(rmn[mi][j], pnv[ni] - 2.0f * acc[mi][ni][j]); \
  } while (0)

  bf16x8 bA[2][2], bB[2][2];
  float pA[2], pB[2];
  LOADB(bA, pA, 0);
#pragma unroll
  for (int t = 0; t < 8; t += 2) {
    LOADB(bB, pB, t + 1);
    COMPUTE(bA, pA);
    if (t + 2 < 8) LOADB(bA, pA, t + 2);
    COMPUTE(bB, pB);
  }
#undef LOADB
#undef COMPUTE

  float tot = __builtin_inff();
#pragma unroll
  for (int mi = 0; mi < 4; ++mi) {
#pragma unroll
    for (int j = 0; j < 4; ++j) {
      const int row = bm + wr * 64 + mi * 16 + (c32 << 2) + j;
      tot = fminf(tot, rmn[mi][j] + pn[row]);
    }
  }
#pragma unroll
  for (int s = 1; s < 64; s <<= 1) tot = fminf(tot, __shfl_xor(tot, s));
  if (lane == 0) sred[wave] = tot;
  __syncthreads();
  if (tid == 0) {
    float m = sred[0];
#pragma unroll
    for (int w = 1; w < 8; ++w) m = fminf(m, sred[w]);
    blockmins[blockIdx.y * 64 + blockIdx.x] = fmaxf(m, 0.0f);
  }
}

// ---------------- flag: reduce 512 block mins; bound < 16 (dist < 4)? -------
// True dist<2 pair implies bound < ~7.1 incl. all rounding -> always caught.
// Benign data: bound ~ 2*chi2_64, P(<16) ~ 1e-21 -> never fires.
__global__ __launch_bounds__(512) void flag_kernel(const float* __restrict__ blockmins,
                                                   int* __restrict__ flag)
{
  const int t = threadIdx.x;
  float m = blockmins[t];
#pragma unroll
  for (int s = 1; s < 64; s <<= 1) m = fminf(m, __shfl_xor(m, s));
  __shared__ float sred[8];
  if ((t & 63) == 0) sred[t >> 6] = m;
  __syncthreads();
  if (t == 0) {
    float g = sred[0];
#pragma unroll
    for (int w = 1; w < 8; ++w) g = fminf(g, sred[w]);
    *flag = (g < 16.0f) ? 1 : 0;
  }
}

// ---------------- cast (flag-gated, grid-stride): fp32 -> bf16 --------------
__global__ __launch_bounds__(256) void cast_kernel(
    const float* __restrict__ o1, const float* __restrict__ o2,
    unsigned short* __restrict__ o1b, unsigned short* __restrict__ o2b,
    const int* __restrict__ flag)
{
  if (*flag == 0) return;
  const int t = threadIdx.x;
  for (int row = blockIdx.x; row < NROWS; row += gridDim.x) {
    const float4 x1 = ((const float4*)(o1 + (size_t)row * DDIM))[t];
    const float4 x2 = ((const float4*)(o2 + (size_t)row * DDIM))[t];
    *(ushort4*)(o1b + (size_t)row * DDIM + t * 4) =
        make_ushort4(f2bf(x1.x), f2bf(x1.y), f2bf(x1.z), f2bf(x1.w));
    *(ushort4*)(o2b + (size_t)row * DDIM + t * 4) =
        make_ushort4(f2bf(x2.x), f2bf(x2.y), f2bf(x2.z), f2bf(x2.w));
  }
}

// ---------------- 128^2 bf16 GEMM (flag-gated; sq stored as bf16) -----------
// Grid-strides over tiles so the early-return dispatch is small.
__global__ __launch_bounds__(256) void gemm_kernel(
    const unsigned short* __restrict__ A, const unsigned short* __restrict__ B,
    const float* __restrict__ a2, const float* __restrict__ b2,
    const int* __restrict__ flag,
    unsigned short* __restrict__ sqbuf, int jBase, int chunkCols)
{
  if (*flag == 0) return;                     // never taken on benign data
  __shared__ __align__(16) unsigned short lA[128 * 32];
  __shared__ __align__(16) unsigned short lB[128 * 32];
  const int tid  = threadIdx.x;
  const int lane = tid & 63;
  const int wave = tid >> 6;
  const int wm = (wave >> 1) * 64;
  const int wn = (wave & 1) * 64;
  const int nct = chunkCols / 128;            // col-tiles per chunk
  const int ntiles = nct * 64;

  for (int tile = blockIdx.x; tile < ntiles; tile += gridDim.x) {
    const int bm = (tile / nct) * 128;
    const int bn = (tile % nct) * 128;

    f32x4 acc[4][4];
#pragma unroll
    for (int mi = 0; mi < 4; ++mi)
#pragma unroll
      for (int ni = 0; ni < 4; ++ni)
        acc[mi][ni] = (f32x4)0.0f;

    const unsigned short* Ab = A + (size_t)bm * DDIM;
    const unsigned short* Bb = B + (size_t)(jBase + bn) * DDIM;
    const int stRow  = lane >> 2;
    const int stColH = (lane & 3) * 8;

    for (int kt = 0; kt < DDIM / 32; ++kt) {
#pragma unroll
      for (int p = 0; p < 2; ++p) {
        const int off = (p * 4 + wave) * 1024;
        const int r0  = off >> 6;
        gload_lds16(Ab + (size_t)(r0 + stRow) * DDIM + kt * 32 + stColH, (char*)lA + off);
        gload_lds16(Bb + (size_t)(r0 + stRow) * DDIM + kt * 32 + stColH, (char*)lB + off);
      }
      __syncthreads();

      bf16x8 af[4], bfr[4];
#pragma unroll
      for (int mi = 0; mi < 4; ++mi) {
        const int r = wm + mi * 16 + (lane & 15);
        af[mi] = *(const bf16x8*)((const char*)lA + r * 64 + (lane >> 4) * 16);
      }
#pragma unroll
      for (int ni = 0; ni < 4; ++ni) {
        const int r = wn + ni * 16 + (lane & 15);
        bfr[ni] = *(const bf16x8*)((const char*)lB + r * 64 + (lane >> 4) * 16);
      }
#pragma unroll
      for (int mi = 0; mi < 4; ++mi)
#pragma unroll
        for (int ni = 0; ni < 4; ++ni)
          acc[mi][ni] = __builtin_amdgcn_mfma_f32_16x16x32_bf16(af[mi], bfr[ni], acc[mi][ni], 0, 0, 0);
      __syncthreads();
    }

#pragma unroll
    for (int mi = 0; mi < 4; ++mi) {
#pragma unroll
      for (int j = 0; j < 4; ++j) {
        const int i = bm + wm + mi * 16 + ((lane >> 4) << 2) + j;
        const float av = a2[i];
#pragma unroll
        for (int ni = 0; ni < 4; ++ni) {
          const int jj = bn + wn + ni * 16 + (lane & 15);
          sqbuf[(size_t)i * chunkCols + jj] = f2bf(av + b2[jBase + jj] - 2.0f * acc[mi][ni][j]);
        }
      }
    }
    __syncthreads();   // LDS reuse across grid-stride tiles
  }
}

// ---------------- exact top-30 per row (fallback; flag-gated, grid-stride) --
template<int VPL>
__global__ __launch_bounds__(64) void select_kernel(
    const unsigned short* __restrict__ sqbuf, const int* __restrict__ flag,
    float* __restrict__ tv, int* __restrict__ ti, int jBase, int isFirst)
{
  if (*flag == 0) return;
  const int lane = threadIdx.x;
  const int CH = VPL * 64;
  for (int row = blockIdx.x; row < NROWS; row += gridDim.x) {
    float v[VPL];
#pragma unroll
    for (int q = 0; q < VPL; ++q)
      v[q] = bf2f(sqbuf[(size_t)row * CH + q * 64 + lane]);
    float cv; int ci;
    if (isFirst) { cv = __builtin_inff(); ci = 0x7fffffff; }
    else {
      cv = (lane < NQ) ? tv[row * 32 + lane] : __builtin_inff();
      ci = (lane < NQ) ? ti[row * 32 + lane] : 0x7fffffff;
    }
    for (int k = 0; k < NQ; ++k) {
      float mv = cv; int mi_ = ci;
#pragma unroll
      for (int q = 0; q < VPL; ++q) {
        const int col = jBase + q * 64 + lane;
        const bool b = (v[q] < mv) || (v[q] == mv && col < mi_);
        mv  = b ? v[q] : mv;
        mi_ = b ? col  : mi_;
      }
#pragma unroll
      for (int s = 1; s < 64; s <<= 1) {
        const float ov = __shfl_xor(mv, s);
        const int   oi = __shfl_xor(mi_, s);
        const bool b = (ov < mv) || (ov == mv && oi < mi_);
        mv  = b ? ov : mv;
        mi_ = b ? oi : mi_;
      }
      if (mi_ == ci) cv = __builtin_inff();
      else if (mi_ >= jBase) {
        const int rel = mi_ - jBase;
        if ((rel & 63) == lane) {
          const int lq = rel >> 6;
#pragma unroll
          for (int q = 0; q < VPL; ++q) if (q == lq) v[q] = __builtin_inff();
        }
      }
      if (lane == 0) { tv[row * 32 + k] = mv; ti[row * 32 + k] = mi_; }
    }
  }
}

// ---------------- final reduction ------------------------------------------
__global__ __launch_bounds__(256) void final_kernel(
    const float* __restrict__ posr, const float* __restrict__ tv,
    const int* __restrict__ ti, const int* __restrict__ rn,
    const int* __restrict__ flag, float* __restrict__ out)
{
  const int t = threadIdx.x;
  const int useNeg = (*flag != 0);
  double ps = 0.0, ns = 0.0;
  for (int r = t; r < NROWS; r += 256) {
    ps += (double)posr[r];
    if (useNeg) {
      int k = rn[r];
      const int sel = ti[r * 32 + k];
      if (sel == r) k = (k + 1) % NQ;
      const float d = sqrtf(fmaxf(tv[r * 32 + k], 0.0f));
      ns += (double)fmaxf(MARGINF - d, 0.0f);
    }
  }
  __shared__ double sp[256], sn[256];
  sp[t] = ps; sn[t] = ns;
  __syncthreads();
  for (int s = 128; s > 0; s >>= 1) {
    if (t < s) { sp[t] += sp[t + s]; sn[t] += sn[t + s]; }
    __syncthreads();
  }
  if (t == 0) out[0] = (float)(sp[0] / NROWS + sn[0] / NROWS);
}

extern "C" void kernel_launch(void* const* d_in, const int* in_sizes, int n_in,
                              void* d_out, int out_size, void* d_ws, size_t ws_size,
                              hipStream_t stream) {
  (void)in_sizes; (void)n_in; (void)out_size;
  const float* o1 = (const float*)d_in[0];
  const float* o2 = (const float*)d_in[1];
  const int*   rn = (const int*)d_in[2];
  float* out = (float*)d_out;

  char* ws = (char*)d_ws;
  size_t off = 0;
  auto alloc = [&](size_t b) { void* p = ws + off; off += (b + 255) & ~(size_t)255; return p; };
  unsigned short* o1b = (unsigned short*)alloc((size_t)NROWS * DDIM * 2);  // 16 MB (fallback only)
  unsigned short* o2b = (unsigned short*)alloc((size_t)NROWS * DDIM * 2);  // 16 MB (fallback only)
  float* a2   = (float*)alloc((size_t)NROWS * 4);
  float* b2   = (float*)alloc((size_t)NROWS * 4);
  float* posr = (float*)alloc((size_t)NROWS * 4);
  float* blockmins = (float*)alloc(512 * 4);
  int*   flag = (int*)alloc(256);
  float* tv   = (float*)alloc((size_t)NROWS * 32 * 4);
  int*   ti   = (int*)alloc((size_t)NROWS * 32 * 4);
  unsigned short* proj = (unsigned short*)alloc((size_t)2 * NROWS * NPROJ * 2);  // 2 MB
  float* pnorm = (float*)alloc((size_t)2 * NROWS * 4);                           // 128 KB
  const size_t remain = ws_size > off ? ws_size - off : 0;
  int chunk;   // sqbuf is bf16 -> chunk 8192 needs 128 MiB
  if      (remain >= (size_t)NROWS * 8192 * 2) chunk = 8192;
  else if (remain >= (size_t)NROWS * 4096 * 2) chunk = 4096;
  else if (remain >= (size_t)NROWS * 2048 * 2) chunk = 2048;
  else if (remain >= (size_t)NROWS * 512 * 2)  chunk = 512;
  else                                         chunk = 128;
  unsigned short* sqbuf = (unsigned short*)(ws + off);

  prep2_kernel<<<NROWS, 256, 0, stream>>>(o1, o2, a2, b2, posr, proj, pnorm);
  gram64_kernel<<<dim3(64, 8), 512, 0, stream>>>(proj, pnorm, blockmins);
  flag_kernel<<<1, 512, 0, stream>>>(blockmins, flag);

  // Fallback chain (flag-gated; never taken on benign data, proven R5).
  cast_kernel<<<1024, 256, 0, stream>>>(o1, o2, o1b, o2b, flag);
  const int nch = NROWS / chunk;
  for (int c = 0; c < nch; ++c) {
    gemm_kernel<<<2048, 256, 0, stream>>>(o1b, o2b, a2, b2, flag,
                                          sqbuf, c * chunk, chunk);
    const int first = (c == 0);
    if      (chunk == 8192) select_kernel<128><<<1024, 64, 0, stream>>>(sqbuf, flag, tv, ti, c * chunk, first);
    else if (chunk == 4096) select_kernel<64><<<1024, 64, 0, stream>>>(sqbuf, flag, tv, ti, c * chunk, first);
    else if (chunk == 2048) select_kernel<32><<<1024, 64, 0, stream>>>(sqbuf, flag, tv, ti, c * chunk, first);
    else if (chunk == 512)  select_kernel<8><<<1024, 64, 0, stream>>>(sqbuf, flag, tv, ti, c * chunk, first);
    else                    select_kernel<2><<<1024, 64, 0, stream>>>(sqbuf, flag, tv, ti, c * chunk, first);
  }
  final_kernel<<<1, 256, 0, stream>>>(posr, tv, ti, rn, flag, out);
}